// Round 4
// baseline (619.187 us; speedup 1.0000x reference)
//
#include <hip/hip_runtime.h>
#include <hip/hip_bf16.h>
#include <math.h>

// ---------------------------------------------------------------------------
// FeatureAttnNet v8 for MI355X (gfx950)
//
// score[b,f] = Y0[b,f] + sum_c cmd[b,c]*Yc[b,f], Y = X @ WKfold^T (BN folded,
// additive BN term cancels in softmax). V GEMM fused with softmax weights.
// v8: fused_attn occupancy 2->3 waves/SIMD: uniform 32-row tiles (16 KB),
//   dbuf 2x16KB (LDS 68.5->36.9 KB); phase-1 WKF streamed as 3 tiles through
//   the same dbuf with per-tile c-term fold into sc[16] (kills acc1[3]=48
//   regs); __launch_bounds__(256,3) caps unified regs at 170.
//   Conflict-free q^(n&31) swizzle kept (R3: bank conflicts 9.67M -> 0).
// setup1 gram: dbuf LDS (2x20KB) + 2-deep register prefetch, 1 barrier/iter.
// Gram: NO atomics — bf16 partials in d_out (scratch before final write).
// ---------------------------------------------------------------------------

typedef float  f32x4   __attribute__((ext_vector_type(4)));
typedef float  f32x16  __attribute__((ext_vector_type(16)));
typedef __bf16 bf16x4  __attribute__((ext_vector_type(4)));
typedef __bf16 bf16x8  __attribute__((ext_vector_type(8)));

#define MFMA16(A, B, C) __builtin_amdgcn_mfma_f32_16x16x32_bf16((A), (B), (C), 0, 0, 0)
#define MFMA32(A, B, C) __builtin_amdgcn_mfma_f32_32x32x16_bf16((A), (B), (C), 0, 0, 0)

#define EPSV 1e-5f

// ---- workspace layout (bytes) ----
#define WS_WV    0x000000u   // 2048*256 bf16 = 1 MiB  [Wvz;Wvh]
#define WS_WKF   0x100000u   // 2*96*256 bf16 = 96 KiB folded K weights (zero-padded)
#define WS_G     0x120000u   // 2*256*256 f32 = 512 KiB
#define WS_CS    0x1A0000u   // 2*256 f32 colsums (zeroed)
#define WS_CMDP  0x1A0800u   // 32*14 f32 cmd partials
#define WS_T     0x1A1800u   // 2048 f32
#define WS_U     0x1A3800u   // 2048 f32
#define WS_WQ2   0x1A5800u   // 256 f32
#define WS_C0    0x1A5C00u   // 64 f32

// async global->LDS, 16B per lane; LDS dest is wave-uniform base + lane*16.
__device__ __forceinline__ void gl_lds16(const void* g, void* l)
{
    __builtin_amdgcn_global_load_lds(
        (const __attribute__((address_space(1))) unsigned int*)g,
        (__attribute__((address_space(3))) unsigned int*)l, 16, 0, 0);
}

// ---------------------------------------------------------------------------
// setup1: blk<128 -> gram partials (bf16 -> d_out); 128..383 -> prepV;
// 384..415 -> cmd stats.
__global__ __launch_bounds__(512, 2) void setup1(const float* __restrict__ feat,
        const float* __restrict__ hid, const float4* __restrict__ cmd,
        const float* __restrict__ Wvz, const float* __restrict__ Wvh,
        __bf16* __restrict__ WV, float* __restrict__ CMDP, float* __restrict__ CS,
        __bf16* __restrict__ Gp)
{
    __shared__ __bf16 T[2 * 256 * 40];        // 40 KiB double buffer
    __shared__ float sm[8][14];
    const int blk = blockIdx.x;
    const int tid = threadIdx.x;

    if (blk >= 384) {                     // ---- cmd stats: 32 blocks ----
        const int b2 = blk - 384;
        float v[14];
#pragma unroll
        for (int k = 0; k < 14; ++k) v[k] = 0.f;
#pragma unroll
        for (int i = 0; i < 4; ++i) {
            float4 c = cmd[(b2 * 4 + i) * 512 + tid];
            v[0] += c.x;  v[1] += c.y;  v[2] += c.z;  v[3] += c.w;
            v[4] += c.x*c.x; v[5] += c.x*c.y; v[6] += c.x*c.z; v[7] += c.x*c.w;
            v[8] += c.y*c.y; v[9] += c.y*c.z; v[10] += c.y*c.w;
            v[11] += c.z*c.z; v[12] += c.z*c.w; v[13] += c.w*c.w;
        }
#pragma unroll
        for (int k = 0; k < 14; ++k) {
            float s = v[k];
#pragma unroll
            for (int off = 32; off; off >>= 1) s += __shfl_xor(s, off);
            if ((tid & 63) == 0) sm[tid >> 6][k] = s;
        }
        __syncthreads();
        if (tid < 14) {
            float s = 0.f;
#pragma unroll
            for (int w = 0; w < 8; ++w) s += sm[w][tid];
            CMDP[b2 * 14 + tid] = s;
        }
        return;
    }
    if (blk >= 128) {                     // ---- prepV: 256 blocks ----
        int t = (blk - 128) * 512 + tid;
        int e = t * 4;
        const float* src = (e < 262144) ? (Wvz + e) : (Wvh + (e - 262144));
        float4 a = *(const float4*)src;
        bf16x4 vv = { (__bf16)a.x, (__bf16)a.y, (__bf16)a.z, (__bf16)a.w };
        *(bf16x4*)(WV + e) = vv;
        return;
    }

    // ---- gram: 128 blocks = 2 mats x 64 chunks x 1024 rows ----
    // Pipelined: T dbuf, 2-deep reg prefetch, 1 barrier per 32-row step.
    const int mat  = blk >> 6;
    const int chunk = blk & 63;
    const float* X = mat ? hid : feat;
    float* cs = CS + mat * 256;
    const int k0   = chunk * 1024;
    const int wid  = tid >> 6, lane = tid & 63, quad = lane >> 4, l15 = lane & 15;
    const int c    = tid & 255;
    const int t8   = tid >> 8;

    f32x4 acc[2][16];
#pragma unroll
    for (int mt = 0; mt < 2; ++mt)
#pragma unroll
        for (int nt = 0; nt < 16; ++nt) acc[mt][nt] = (f32x4){0.f, 0.f, 0.f, 0.f};

    const float* Xc = X + (size_t)k0 * 256 + c;   // element (k, c) at Xc[k*256]
    float ra[16], rb[16];
    float clsum = 0.f;

#define GRAM_LOAD(R, IT) do { \
        const float* p_ = Xc + (size_t)(IT) * 32 * 256; \
        _Pragma("unroll") \
        for (int i_ = 0; i_ < 16; ++i_) (R)[i_] = p_[(size_t)(t8 + 2 * i_) * 256]; \
    } while (0)
#define GRAM_WRITE(R, BUFO) do { \
        _Pragma("unroll") \
        for (int i_ = 0; i_ < 16; ++i_) { \
            float x_ = (R)[i_]; clsum += x_; \
            T[(BUFO) + c * 40 + t8 + 2 * i_] = (__bf16)x_; } \
    } while (0)
#define GRAM_MFMA(BUFO) do { \
        const __bf16* Tb_ = &T[(BUFO)]; \
        bf16x8 a0_ = *(const bf16x8*)&Tb_[(wid * 32 +      l15) * 40 + quad * 8]; \
        bf16x8 a1_ = *(const bf16x8*)&Tb_[(wid * 32 + 16 + l15) * 40 + quad * 8]; \
        _Pragma("unroll") \
        for (int nt_ = 0; nt_ < 16; ++nt_) { \
            bf16x8 b_ = *(const bf16x8*)&Tb_[(nt_ * 16 + l15) * 40 + quad * 8]; \
            acc[0][nt_] = MFMA16(a0_, b_, acc[0][nt_]); \
            acc[1][nt_] = MFMA16(a1_, b_, acc[1][nt_]); } \
    } while (0)

    GRAM_LOAD(ra, 0);                     // it0
    GRAM_LOAD(rb, 1);                     // it1
    GRAM_WRITE(ra, 0);                    // it0 -> T0
    GRAM_LOAD(ra, 2);                     // it2 (consumed body B of it2=0)
    __syncthreads();

    for (int it2 = 0; it2 < 16; ++it2) {
        // body A: write rb (it 2*it2+1) -> T1; refill rb <- it 2*it2+3; MFMA T0
        GRAM_WRITE(rb, 10240);
        if (it2 < 15) GRAM_LOAD(rb, 2 * it2 + 3);
        GRAM_MFMA(0);
        __syncthreads();
        // body B: write ra (it 2*it2+2) -> T0; refill ra <- it 2*it2+4; MFMA T1
        if (it2 < 15) {
            GRAM_WRITE(ra, 0);
            if (it2 < 14) GRAM_LOAD(ra, 2 * it2 + 4);
        }
        GRAM_MFMA(10240);
        __syncthreads();
    }
#undef GRAM_LOAD
#undef GRAM_WRITE
#undef GRAM_MFMA

    atomicAdd(&cs[c], clsum);             // 512 addrs, 128-way — cheap
    __bf16* outp = Gp + (size_t)blk * 65536;
#pragma unroll
    for (int mt = 0; mt < 2; ++mt)
#pragma unroll
        for (int nt = 0; nt < 16; ++nt)
#pragma unroll
            for (int r = 0; r < 4; ++r) {
                int gi = wid * 32 + mt * 16 + quad * 4 + r;
                int gj = nt * 16 + l15;
                outp[gi * 256 + gj] = (__bf16)acc[mt][nt][r];
            }
}

// ---------------------------------------------------------------------------
__global__ void gram_reduce(const __bf16* __restrict__ Gp, float* __restrict__ G)
{
    int o = blockIdx.x * 256 + threadIdx.x;      // 512 x 256 = 131072
    int mat = o >> 16, e = o & 65535;
    const __bf16* p = Gp + (size_t)mat * 64 * 65536 + e;
    float s = 0.f;
#pragma unroll 8
    for (int c = 0; c < 64; ++c) s += (float)p[(size_t)c * 65536];
    G[o] = s;
}

// ---------------------------------------------------------------------------
__global__ void rowstats(const float* __restrict__ Wkz, const float* __restrict__ Wkh,
        const float* __restrict__ G, const float* __restrict__ CS,
        float* __restrict__ Tout, float* __restrict__ Uout)
{
    const int blk = blockIdx.x;               // 256 blocks
    const int mat = blk >> 7, jg = blk & 127;
    const float* Wsrc = (mat ? Wkh : Wkz) + (size_t)jg * 8 * 256;
    const float* Gm = G + (size_t)mat * 65536;
    const float* cs = CS + mat * 256;
    __shared__ float wlT[256 * 8];
    __shared__ float red[4][16];
    const int tid = threadIdx.x, wid = tid >> 6, lane = tid & 63;
#pragma unroll
    for (int jj = 0; jj < 8; ++jj) wlT[tid * 8 + jj] = Wsrc[jj * 256 + tid];
    __syncthreads();
    float inner[8];
#pragma unroll
    for (int jj = 0; jj < 8; ++jj) inner[jj] = 0.f;
    for (int r = 0; r < 256; ++r) {
        float g = Gm[r * 256 + tid];
        float4 w0 = *(const float4*)&wlT[r * 8];
        float4 w1 = *(const float4*)&wlT[r * 8 + 4];
        inner[0] = fmaf(w0.x, g, inner[0]); inner[1] = fmaf(w0.y, g, inner[1]);
        inner[2] = fmaf(w0.z, g, inner[2]); inner[3] = fmaf(w0.w, g, inner[3]);
        inner[4] = fmaf(w1.x, g, inner[4]); inner[5] = fmaf(w1.y, g, inner[5]);
        inner[6] = fmaf(w1.z, g, inner[6]); inner[7] = fmaf(w1.w, g, inner[7]);
    }
    float cst = cs[tid];
#pragma unroll
    for (int jj = 0; jj < 8; ++jj) {
        float wme = wlT[tid * 8 + jj];
        float p = wme * inner[jj];
        float u = wme * cst;
#pragma unroll
        for (int off = 32; off; off >>= 1) { p += __shfl_xor(p, off); u += __shfl_xor(u, off); }
        if (lane == 0) { red[wid][jj] = p; red[wid][jj + 8] = u; }
    }
    __syncthreads();
    if (tid < 16) {
        float s = red[0][tid] + red[1][tid] + red[2][tid] + red[3][tid];
        int jj = tid & 7;
        int j = mat * 1024 + jg * 8 + jj;
        if (tid < 8) Tout[j] = s; else Uout[j] = s;
    }
}

// ---------------------------------------------------------------------------
__global__ void finalize_kernel(const float* __restrict__ Wq,
        const float* __restrict__ gQ, const float* __restrict__ bQ,
        const float* __restrict__ gK, const float* __restrict__ bK,
        const float* __restrict__ CMDP, const float* __restrict__ T,
        const float* __restrict__ U, float* __restrict__ Wq2, float* __restrict__ C0)
{
    __shared__ float s14[14];
    const int d = threadIdx.x;
    if (d < 14) {
        float s = 0.f;
        for (int b = 0; b < 32; ++b) s += CMDP[b * 14 + d];
        s14[d] = s;
    }
    __syncthreads();
    float s4[4] = { s14[0], s14[1], s14[2], s14[3] };
    float gc[4][4];
    gc[0][0] = s14[4];
    gc[0][1] = gc[1][0] = s14[5];
    gc[0][2] = gc[2][0] = s14[6];
    gc[0][3] = gc[3][0] = s14[7];
    gc[1][1] = s14[8];
    gc[1][2] = gc[2][1] = s14[9];
    gc[1][3] = gc[3][1] = s14[10];
    gc[2][2] = s14[11];
    gc[2][3] = gc[3][2] = s14[12];
    gc[3][3] = s14[13];
    float wq[4];
#pragma unroll
    for (int c = 0; c < 4; ++c) wq[c] = Wq[d * 4 + c];
    const float invB = 1.0f / 65536.0f;
    float mQ = (wq[0]*s4[0] + wq[1]*s4[1] + wq[2]*s4[2] + wq[3]*s4[3]) * invB;
    float eq2 = 0.f;
#pragma unroll
    for (int c = 0; c < 4; ++c)
#pragma unroll
        for (int c2 = 0; c2 < 4; ++c2) eq2 += wq[c] * wq[c2] * gc[c][c2];
    eq2 *= invB;
    float vQ  = eq2 - mQ * mQ;
    float aQ  = gQ[d] / sqrtf(vQ + EPSV);
    float bQv = bQ[d] - mQ * aQ;
    float S2 = 0.f, S1 = 0.f;
#pragma unroll
    for (int f = 0; f < 32; ++f) { S2 += T[f * 64 + d]; S1 += U[f * 64 + d]; }
    const float invBF = 1.0f / (65536.0f * 32.0f);
    float e2 = S2 * invBF, mK = S1 * invBF;
    float vK = e2 - mK * mK;
    float aK = gK[d] / sqrtf(vK + EPSV);
    float c1 = aQ * aK * 0.125f;      // 1/sqrt(64) folded in
    C0[d] = bQv * aK * 0.125f;
#pragma unroll
    for (int c = 0; c < 4; ++c) Wq2[d * 4 + c] = c1 * wq[c];
}

// ---------------------------------------------------------------------------
// WKF[h][r = c*16 + fl][k] = sum_d coef_c[d]*W_h[fl*64+d][k]; rows 80..95 = 0.
__global__ void foldK(const float* __restrict__ Wkz, const float* __restrict__ Wkh,
                      const float* __restrict__ Wq2, const float* __restrict__ C0,
                      __bf16* __restrict__ WKF)
{
    const int blk = blockIdx.x;               // 192
    const int h = blk / 96, rr = blk % 96;
    const int k = threadIdx.x;
    float s = 0.f;
    if (rr < 80) {
        const int c = rr >> 4, fl = rr & 15;
        const float* Wsrc = (h ? Wkh : Wkz) + (size_t)fl * 64 * 256;
        for (int d = 0; d < 64; ++d) {
            float coef = (c == 0) ? C0[d] : Wq2[d * 4 + (c - 1)];
            s = fmaf(coef, Wsrc[d * 256 + k], s);
        }
    }
    WKF[(size_t)(h * 96 + rr) * 256 + k] = (__bf16)s;
}

// ---------------------------------------------------------------------------
// fused_attn v8: 512 blocks x 256 threads; wave = 32 rows; uniform 32-row
// tiles (16 KB) through a 2x16KB dbuf; per half: 3 WKF tiles (c-term fold
// into sc[16] per tile, exp epilogue after tile 2) + 32 V tiles. Staging via
// global_load_lds, pre-swizzled source q^(n&31) (conflict-free). 1 barrier
// per tile. launch_bounds(256,3): 3 waves/SIMD target.
__global__ __launch_bounds__(256, 3) void fused_attn(
        const float* __restrict__ feat, const float* __restrict__ hid,
        const float4* __restrict__ cmd, const __bf16* __restrict__ WV,
        const __bf16* __restrict__ WKF, float* __restrict__ out)
{
    __shared__ __bf16 BUF[2 * 8192];          // 32 KiB dbuf (tile = 32 rows)
    __shared__ __bf16 WGTs[16 * 132];         // 4.2 KiB, [f][row], padded
    const int tid  = threadIdx.x;
    const int wid  = tid >> 6, lane = tid & 63;
    const int l5   = lane & 31, hi = lane >> 5;
    const int fl   = l5 & 15;
    const bool low = (l5 < 16);
    const int wrow = (blockIdx.x << 7) + (wid << 5);   // wave's 32 rows

    // Stage chunk i of a 32-row tile (per wave): rows n = wid*2 + i*8 + hi,
    // 64 lanes x 16B -> 1KiB linear LDS at row*256. Source slot pre-swizzled
    // with the full-row involution s^(n&31); reads use the same xor: 32 lanes
    // hit 32 distinct 16B slots -> conflict-free (verified R3: conflicts=0).
#define STAGE_CHUNK(SRC, DSTBASE, I) do { \
        int n_ = (wid << 1) + ((I) << 3) + hi; \
        gl_lds16((SRC) + n_ * 256 + ((l5 ^ n_) << 3), \
                 &BUF[(DSTBASE) + (((wid << 1) + ((I) << 3)) << 8)]); \
    } while (0)

    float l_i[16];
    f32x16 s_acc[2];
#pragma unroll
    for (int r = 0; r < 16; ++r) { l_i[r] = 0.f; s_acc[0][r] = 0.f; s_acc[1][r] = 0.f; }

    for (int h = 0; h < 2; ++h) {
        const float* X = h ? hid : feat;
        const __bf16* Wkf  = WKF + ((size_t)h * 96 << 8);
        const __bf16* Vbase = WV + ((size_t)h << 18);   // h*1024 rows

        // ---- A fragments (32x32x16): row wrow+l5, k = u*16 + hi*8 + j ----
        bf16x8 a2[16];
#pragma unroll
        for (int u = 0; u < 16; ++u) {
            const float* p = X + ((size_t)(wrow + l5) << 8) + u * 16 + hi * 8;
            float4 x0 = *(const float4*)p;
            float4 x1 = *(const float4*)(p + 4);
            a2[u] = (bf16x8){ (__bf16)x0.x, (__bf16)x0.y, (__bf16)x0.z, (__bf16)x0.w,
                              (__bf16)x1.x, (__bf16)x1.y, (__bf16)x1.z, (__bf16)x1.w };
        }

        float sc[16];
#pragma unroll
        for (int r = 0; r < 16; ++r) sc[r] = 0.f;

        // prologue: stage tile 0 (WKF rows 0-31) into buf0
        __syncthreads();                      // prior readers of BUF done
#pragma unroll
        for (int i = 0; i < 4; ++i)
            STAGE_CHUNK(Wkf, 0, i);

        // ---- 35 tiles: t=0..2 WKF (score fold), t=3..34 V (weighted acc) ----
        for (int t = 0; t < 35; ++t) {
            const int bufsel = (t & 1) << 13;
            __syncthreads();                  // cur tile staged; prev reads done
            if (t < 34) {                     // prefetch next tile -> other buf
                const __bf16* nsrc = (t < 2) ? (Wkf + ((t + 1) << 13))
                                             : (Vbase + ((size_t)(t - 2) << 13));
                const int nsel = bufsel ^ 8192;
#pragma unroll
                for (int i = 0; i < 4; ++i)
                    STAGE_CHUNK(nsrc, nsel, i);
            }
            __builtin_amdgcn_sched_barrier(0);   // pin prefetch-issue first
            f32x16 acc;
#pragma unroll
            for (int r = 0; r < 16; ++r) acc[r] = 0.f;
            __builtin_amdgcn_s_setprio(1);
#pragma unroll
            for (int ks = 0; ks < 16; ++ks) {
                bf16x8 b = *(const bf16x8*)&BUF[bufsel + l5 * 256
                                                + (((ks * 2 + hi) ^ l5) << 3)];
                acc = MFMA32(a2[ks], b, acc);
            }
            __builtin_amdgcn_s_setprio(0);

            if (t < 3) {
                // fold this WKF tile's c-terms into sc.
                // tile t cols n = t*32+l5: c = 2t (low 16) / 2t+1 (high 16).
#pragma unroll
                for (int g = 0; g < 4; ++g)
#pragma unroll
                    for (int j = 0; j < 4; ++j) {
                        const int r = g * 4 + j;
                        float4 cm = cmd[wrow + j + 8 * g + 4 * hi];
                        float e0 = acc[r];
                        float e1 = __shfl_xor(e0, 16);
                        float t0 = low ? e0 : e1;
                        float t1 = low ? e1 : e0;
                        if (t == 0)      sc[r] += t0 + cm.x * t1;
                        else if (t == 1) sc[r] += cm.y * t0 + cm.z * t1;
                        else             sc[r] += cm.w * t0;   // t1 = padding
                    }
                if (t == 2) {
                    // exp epilogue: weights to WGTs (own wave's rows), l sums
#pragma unroll
                    for (int g = 0; g < 4; ++g) {
                        bf16x4 wv4;
#pragma unroll
                        for (int j = 0; j < 4; ++j) {
                            const int r = g * 4 + j;
                            float w = __expf(sc[r]);
                            wv4[j] = (__bf16)w;
                            float ws = w;
                            ws += __shfl_xor(ws, 1); ws += __shfl_xor(ws, 2);
                            ws += __shfl_xor(ws, 4); ws += __shfl_xor(ws, 8);
                            l_i[r] += ws;
                        }
                        if (low) *(bf16x4*)&WGTs[fl * 132 + (wid << 5)
                                                 + 8 * g + 4 * hi] = wv4;
                    }
                }
            } else {
                const int v    = t - 3;        // 0..31
                const int dsel = v & 1;        // d 0-31 / 32-63
                const int f2   = v >> 1;       // f index within half
#pragma unroll
                for (int g = 0; g < 4; ++g) {
                    bf16x4 wv = *(const bf16x4*)&WGTs[f2 * 132 + (wid << 5)
                                                      + 8 * g + 4 * hi];
#pragma unroll
                    for (int j = 0; j < 4; ++j) {
                        float w = (float)wv[j];
                        if (dsel == 0) s_acc[0][g * 4 + j] += w * acc[g * 4 + j];
                        else           s_acc[1][g * 4 + j] += w * acc[g * 4 + j];
                    }
                }
            }
        }
    }
#undef STAGE_CHUNK

    // ---- epilogue: divide by l, store ----
#pragma unroll
    for (int g = 0; g < 4; ++g)
#pragma unroll
        for (int j = 0; j < 4; ++j) {
            const int r = g * 4 + j;
            float inv = 1.0f / l_i[r];
            size_t row = (size_t)(wrow + j + 8 * g + 4 * hi);
            out[(row << 6) + l5]      = s_acc[0][r] * inv;
            out[(row << 6) + 32 + l5] = s_acc[1][r] * inv;
        }
}

// ---------------------------------------------------------------------------
extern "C" void kernel_launch(void* const* d_in, const int* in_sizes, int n_in,
                              void* d_out, int out_size, void* d_ws, size_t ws_size,
                              hipStream_t stream)
{
    (void)in_sizes; (void)n_in; (void)out_size; (void)ws_size;
    const float* feature = (const float*)d_in[0];
    const float* hidden  = (const float*)d_in[1];
    const float* command = (const float*)d_in[2];
    const float* Wq      = (const float*)d_in[3];
    const float* Wkz     = (const float*)d_in[4];
    const float* Wkh     = (const float*)d_in[5];
    const float* Wvz     = (const float*)d_in[6];
    const float* Wvh     = (const float*)d_in[7];
    const float* gammaQ  = (const float*)d_in[8];
    const float* betaQ   = (const float*)d_in[9];
    const float* gammaK  = (const float*)d_in[10];
    const float* betaK   = (const float*)d_in[11];

    char* ws = (char*)d_ws;
    __bf16* WV   = (__bf16*)(ws + WS_WV);
    __bf16* WKF  = (__bf16*)(ws + WS_WKF);
    float*  G    = (float*)(ws + WS_G);
    float*  CS   = (float*)(ws + WS_CS);
    float*  CMDP = (float*)(ws + WS_CMDP);
    float*  Tj   = (float*)(ws + WS_T);
    float*  Uj   = (float*)(ws + WS_U);
    float*  Wq2  = (float*)(ws + WS_WQ2);
    float*  C0   = (float*)(ws + WS_C0);
    float*  outp = (float*)d_out;
    __bf16* Gp   = (__bf16*)d_out;            // 16 MB scratch before final write

    hipMemsetAsync(ws + WS_CS, 0, 0x800, stream);
    setup1<<<416, 512, 0, stream>>>(feature, hidden, (const float4*)command,
                                    Wvz, Wvh, WV, CMDP, CS, Gp);
    gram_reduce<<<512, 256, 0, stream>>>(Gp, G);
    rowstats<<<256, 256, 0, stream>>>(Wkz, Wkh, G, CS, Tj, Uj);
    finalize_kernel<<<1, 64, 0, stream>>>(Wq, gammaQ, betaQ, gammaK, betaK,
                                          CMDP, Tj, Uj, Wq2, C0);
    foldK<<<192, 256, 0, stream>>>(Wkz, Wkh, Wq2, C0, WKF);
    fused_attn<<<512, 256, 0, stream>>>(feature, hidden, (const float4*)command,
                                        WV, WKF, outp);
}

// Round 5
// 501.246 us; speedup vs baseline: 1.2353x; 1.2353x over previous
//
#include <hip/hip_runtime.h>
#include <hip/hip_bf16.h>
#include <math.h>

// ---------------------------------------------------------------------------
// FeatureAttnNet v9 for MI355X (gfx950)
//
// score[b,f] = Y0[b,f] + sum_c cmd[b,c]*Yc[b,f], Y = X @ WKfold^T (BN folded,
// additive BN term cancels in softmax). V GEMM fused with softmax weights.
// v9: fused_attn: NO LDS staging, NO barriers. B operands (WKF 96KB, WV 1MB)
//   are L2-resident (4MB/XCD) and read directly as 16B global loads with
//   immediate ks*32B offsets (guide Common-mistake #7: staging L2-fit data
//   is pure overhead). Waves fully independent; latency hidden by MLP.
//   WGTs (4KB LDS) is wave-private (same wid writes+reads) -> no syncthreads.
//   v8's 32-row tiles + launch_bounds(256,3) REVERTED (grid caps waves/CU at
//   8; the reg budget forced hot-loop spills: 431us).
// setup1 gram: dbuf LDS (2x20KB) + 2-deep register prefetch, 1 barrier/iter.
// Gram: NO atomics — bf16 partials in d_out (scratch before final write).
// ---------------------------------------------------------------------------

typedef float  f32x4   __attribute__((ext_vector_type(4)));
typedef float  f32x16  __attribute__((ext_vector_type(16)));
typedef __bf16 bf16x4  __attribute__((ext_vector_type(4)));
typedef __bf16 bf16x8  __attribute__((ext_vector_type(8)));

#define MFMA16(A, B, C) __builtin_amdgcn_mfma_f32_16x16x32_bf16((A), (B), (C), 0, 0, 0)
#define MFMA32(A, B, C) __builtin_amdgcn_mfma_f32_32x32x16_bf16((A), (B), (C), 0, 0, 0)

#define EPSV 1e-5f

// ---- workspace layout (bytes) ----
#define WS_WV    0x000000u   // 2048*256 bf16 = 1 MiB  [Wvz;Wvh]
#define WS_WKF   0x100000u   // 2*96*256 bf16 = 96 KiB folded K weights (zero-padded)
#define WS_G     0x120000u   // 2*256*256 f32 = 512 KiB
#define WS_CS    0x1A0000u   // 2*256 f32 colsums (zeroed)
#define WS_CMDP  0x1A0800u   // 32*14 f32 cmd partials
#define WS_T     0x1A1800u   // 2048 f32
#define WS_U     0x1A3800u   // 2048 f32
#define WS_WQ2   0x1A5800u   // 256 f32
#define WS_C0    0x1A5C00u   // 64 f32

// ---------------------------------------------------------------------------
// setup1: blk<128 -> gram partials (bf16 -> d_out); 128..383 -> prepV;
// 384..415 -> cmd stats.
__global__ __launch_bounds__(512, 2) void setup1(const float* __restrict__ feat,
        const float* __restrict__ hid, const float4* __restrict__ cmd,
        const float* __restrict__ Wvz, const float* __restrict__ Wvh,
        __bf16* __restrict__ WV, float* __restrict__ CMDP, float* __restrict__ CS,
        __bf16* __restrict__ Gp)
{
    __shared__ __bf16 T[2 * 256 * 40];        // 40 KiB double buffer
    __shared__ float sm[8][14];
    const int blk = blockIdx.x;
    const int tid = threadIdx.x;

    if (blk >= 384) {                     // ---- cmd stats: 32 blocks ----
        const int b2 = blk - 384;
        float v[14];
#pragma unroll
        for (int k = 0; k < 14; ++k) v[k] = 0.f;
#pragma unroll
        for (int i = 0; i < 4; ++i) {
            float4 c = cmd[(b2 * 4 + i) * 512 + tid];
            v[0] += c.x;  v[1] += c.y;  v[2] += c.z;  v[3] += c.w;
            v[4] += c.x*c.x; v[5] += c.x*c.y; v[6] += c.x*c.z; v[7] += c.x*c.w;
            v[8] += c.y*c.y; v[9] += c.y*c.z; v[10] += c.y*c.w;
            v[11] += c.z*c.z; v[12] += c.z*c.w; v[13] += c.w*c.w;
        }
#pragma unroll
        for (int k = 0; k < 14; ++k) {
            float s = v[k];
#pragma unroll
            for (int off = 32; off; off >>= 1) s += __shfl_xor(s, off);
            if ((tid & 63) == 0) sm[tid >> 6][k] = s;
        }
        __syncthreads();
        if (tid < 14) {
            float s = 0.f;
#pragma unroll
            for (int w = 0; w < 8; ++w) s += sm[w][tid];
            CMDP[b2 * 14 + tid] = s;
        }
        return;
    }
    if (blk >= 128) {                     // ---- prepV: 256 blocks ----
        int t = (blk - 128) * 512 + tid;
        int e = t * 4;
        const float* src = (e < 262144) ? (Wvz + e) : (Wvh + (e - 262144));
        float4 a = *(const float4*)src;
        bf16x4 vv = { (__bf16)a.x, (__bf16)a.y, (__bf16)a.z, (__bf16)a.w };
        *(bf16x4*)(WV + e) = vv;
        return;
    }

    // ---- gram: 128 blocks = 2 mats x 64 chunks x 1024 rows ----
    // Pipelined: T dbuf, 2-deep reg prefetch, 1 barrier per 32-row step.
    const int mat  = blk >> 6;
    const int chunk = blk & 63;
    const float* X = mat ? hid : feat;
    float* cs = CS + mat * 256;
    const int k0   = chunk * 1024;
    const int wid  = tid >> 6, lane = tid & 63, quad = lane >> 4, l15 = lane & 15;
    const int c    = tid & 255;
    const int t8   = tid >> 8;

    f32x4 acc[2][16];
#pragma unroll
    for (int mt = 0; mt < 2; ++mt)
#pragma unroll
        for (int nt = 0; nt < 16; ++nt) acc[mt][nt] = (f32x4){0.f, 0.f, 0.f, 0.f};

    const float* Xc = X + (size_t)k0 * 256 + c;   // element (k, c) at Xc[k*256]
    float ra[16], rb[16];
    float clsum = 0.f;

#define GRAM_LOAD(R, IT) do { \
        const float* p_ = Xc + (size_t)(IT) * 32 * 256; \
        _Pragma("unroll") \
        for (int i_ = 0; i_ < 16; ++i_) (R)[i_] = p_[(size_t)(t8 + 2 * i_) * 256]; \
    } while (0)
#define GRAM_WRITE(R, BUFO) do { \
        _Pragma("unroll") \
        for (int i_ = 0; i_ < 16; ++i_) { \
            float x_ = (R)[i_]; clsum += x_; \
            T[(BUFO) + c * 40 + t8 + 2 * i_] = (__bf16)x_; } \
    } while (0)
#define GRAM_MFMA(BUFO) do { \
        const __bf16* Tb_ = &T[(BUFO)]; \
        bf16x8 a0_ = *(const bf16x8*)&Tb_[(wid * 32 +      l15) * 40 + quad * 8]; \
        bf16x8 a1_ = *(const bf16x8*)&Tb_[(wid * 32 + 16 + l15) * 40 + quad * 8]; \
        _Pragma("unroll") \
        for (int nt_ = 0; nt_ < 16; ++nt_) { \
            bf16x8 b_ = *(const bf16x8*)&Tb_[(nt_ * 16 + l15) * 40 + quad * 8]; \
            acc[0][nt_] = MFMA16(a0_, b_, acc[0][nt_]); \
            acc[1][nt_] = MFMA16(a1_, b_, acc[1][nt_]); } \
    } while (0)

    GRAM_LOAD(ra, 0);                     // it0
    GRAM_LOAD(rb, 1);                     // it1
    GRAM_WRITE(ra, 0);                    // it0 -> T0
    GRAM_LOAD(ra, 2);                     // it2 (consumed body B of it2=0)
    __syncthreads();

    for (int it2 = 0; it2 < 16; ++it2) {
        // body A: write rb (it 2*it2+1) -> T1; refill rb <- it 2*it2+3; MFMA T0
        GRAM_WRITE(rb, 10240);
        if (it2 < 15) GRAM_LOAD(rb, 2 * it2 + 3);
        GRAM_MFMA(0);
        __syncthreads();
        // body B: write ra (it 2*it2+2) -> T0; refill ra <- it 2*it2+4; MFMA T1
        if (it2 < 15) {
            GRAM_WRITE(ra, 0);
            if (it2 < 14) GRAM_LOAD(ra, 2 * it2 + 4);
        }
        GRAM_MFMA(10240);
        __syncthreads();
    }
#undef GRAM_LOAD
#undef GRAM_WRITE
#undef GRAM_MFMA

    atomicAdd(&cs[c], clsum);             // 512 addrs, 128-way — cheap
    __bf16* outp = Gp + (size_t)blk * 65536;
#pragma unroll
    for (int mt = 0; mt < 2; ++mt)
#pragma unroll
        for (int nt = 0; nt < 16; ++nt)
#pragma unroll
            for (int r = 0; r < 4; ++r) {
                int gi = wid * 32 + mt * 16 + quad * 4 + r;
                int gj = nt * 16 + l15;
                outp[gi * 256 + gj] = (__bf16)acc[mt][nt][r];
            }
}

// ---------------------------------------------------------------------------
__global__ void gram_reduce(const __bf16* __restrict__ Gp, float* __restrict__ G)
{
    int o = blockIdx.x * 256 + threadIdx.x;      // 512 x 256 = 131072
    int mat = o >> 16, e = o & 65535;
    const __bf16* p = Gp + (size_t)mat * 64 * 65536 + e;
    float s = 0.f;
#pragma unroll 8
    for (int c = 0; c < 64; ++c) s += (float)p[(size_t)c * 65536];
    G[o] = s;
}

// ---------------------------------------------------------------------------
__global__ void rowstats(const float* __restrict__ Wkz, const float* __restrict__ Wkh,
        const float* __restrict__ G, const float* __restrict__ CS,
        float* __restrict__ Tout, float* __restrict__ Uout)
{
    const int blk = blockIdx.x;               // 256 blocks
    const int mat = blk >> 7, jg = blk & 127;
    const float* Wsrc = (mat ? Wkh : Wkz) + (size_t)jg * 8 * 256;
    const float* Gm = G + (size_t)mat * 65536;
    const float* cs = CS + mat * 256;
    __shared__ float wlT[256 * 8];
    __shared__ float red[4][16];
    const int tid = threadIdx.x, wid = tid >> 6, lane = tid & 63;
#pragma unroll
    for (int jj = 0; jj < 8; ++jj) wlT[tid * 8 + jj] = Wsrc[jj * 256 + tid];
    __syncthreads();
    float inner[8];
#pragma unroll
    for (int jj = 0; jj < 8; ++jj) inner[jj] = 0.f;
    for (int r = 0; r < 256; ++r) {
        float g = Gm[r * 256 + tid];
        float4 w0 = *(const float4*)&wlT[r * 8];
        float4 w1 = *(const float4*)&wlT[r * 8 + 4];
        inner[0] = fmaf(w0.x, g, inner[0]); inner[1] = fmaf(w0.y, g, inner[1]);
        inner[2] = fmaf(w0.z, g, inner[2]); inner[3] = fmaf(w0.w, g, inner[3]);
        inner[4] = fmaf(w1.x, g, inner[4]); inner[5] = fmaf(w1.y, g, inner[5]);
        inner[6] = fmaf(w1.z, g, inner[6]); inner[7] = fmaf(w1.w, g, inner[7]);
    }
    float cst = cs[tid];
#pragma unroll
    for (int jj = 0; jj < 8; ++jj) {
        float wme = wlT[tid * 8 + jj];
        float p = wme * inner[jj];
        float u = wme * cst;
#pragma unroll
        for (int off = 32; off; off >>= 1) { p += __shfl_xor(p, off); u += __shfl_xor(u, off); }
        if (lane == 0) { red[wid][jj] = p; red[wid][jj + 8] = u; }
    }
    __syncthreads();
    if (tid < 16) {
        float s = red[0][tid] + red[1][tid] + red[2][tid] + red[3][tid];
        int jj = tid & 7;
        int j = mat * 1024 + jg * 8 + jj;
        if (tid < 8) Tout[j] = s; else Uout[j] = s;
    }
}

// ---------------------------------------------------------------------------
__global__ void finalize_kernel(const float* __restrict__ Wq,
        const float* __restrict__ gQ, const float* __restrict__ bQ,
        const float* __restrict__ gK, const float* __restrict__ bK,
        const float* __restrict__ CMDP, const float* __restrict__ T,
        const float* __restrict__ U, float* __restrict__ Wq2, float* __restrict__ C0)
{
    __shared__ float s14[14];
    const int d = threadIdx.x;
    if (d < 14) {
        float s = 0.f;
        for (int b = 0; b < 32; ++b) s += CMDP[b * 14 + d];
        s14[d] = s;
    }
    __syncthreads();
    float s4[4] = { s14[0], s14[1], s14[2], s14[3] };
    float gc[4][4];
    gc[0][0] = s14[4];
    gc[0][1] = gc[1][0] = s14[5];
    gc[0][2] = gc[2][0] = s14[6];
    gc[0][3] = gc[3][0] = s14[7];
    gc[1][1] = s14[8];
    gc[1][2] = gc[2][1] = s14[9];
    gc[1][3] = gc[3][1] = s14[10];
    gc[2][2] = s14[11];
    gc[2][3] = gc[3][2] = s14[12];
    gc[3][3] = s14[13];
    float wq[4];
#pragma unroll
    for (int c = 0; c < 4; ++c) wq[c] = Wq[d * 4 + c];
    const float invB = 1.0f / 65536.0f;
    float mQ = (wq[0]*s4[0] + wq[1]*s4[1] + wq[2]*s4[2] + wq[3]*s4[3]) * invB;
    float eq2 = 0.f;
#pragma unroll
    for (int c = 0; c < 4; ++c)
#pragma unroll
        for (int c2 = 0; c2 < 4; ++c2) eq2 += wq[c] * wq[c2] * gc[c][c2];
    eq2 *= invB;
    float vQ  = eq2 - mQ * mQ;
    float aQ  = gQ[d] / sqrtf(vQ + EPSV);
    float bQv = bQ[d] - mQ * aQ;
    float S2 = 0.f, S1 = 0.f;
#pragma unroll
    for (int f = 0; f < 32; ++f) { S2 += T[f * 64 + d]; S1 += U[f * 64 + d]; }
    const float invBF = 1.0f / (65536.0f * 32.0f);
    float e2 = S2 * invBF, mK = S1 * invBF;
    float vK = e2 - mK * mK;
    float aK = gK[d] / sqrtf(vK + EPSV);
    float c1 = aQ * aK * 0.125f;      // 1/sqrt(64) folded in
    C0[d] = bQv * aK * 0.125f;
#pragma unroll
    for (int c = 0; c < 4; ++c) Wq2[d * 4 + c] = c1 * wq[c];
}

// ---------------------------------------------------------------------------
// WKF[h][r = c*16 + fl][k] = sum_d coef_c[d]*W_h[fl*64+d][k]; rows 80..95 = 0.
__global__ void foldK(const float* __restrict__ Wkz, const float* __restrict__ Wkh,
                      const float* __restrict__ Wq2, const float* __restrict__ C0,
                      __bf16* __restrict__ WKF)
{
    const int blk = blockIdx.x;               // 192
    const int h = blk / 96, rr = blk % 96;
    const int k = threadIdx.x;
    float s = 0.f;
    if (rr < 80) {
        const int c = rr >> 4, fl = rr & 15;
        const float* Wsrc = (h ? Wkh : Wkz) + (size_t)fl * 64 * 256;
        for (int d = 0; d < 64; ++d) {
            float coef = (c == 0) ? C0[d] : Wq2[d * 4 + (c - 1)];
            s = fmaf(coef, Wsrc[d * 256 + k], s);
        }
    }
    WKF[(size_t)(h * 96 + rr) * 256 + k] = (__bf16)s;
}

// ---------------------------------------------------------------------------
// fused_attn v9: 512 blocks x 256 threads; wave = 32 rows; NO LDS staging,
// NO barriers. B fragments read directly from L2-resident WKF/WV as 16B
// global loads (row base pointer + ks*32B immediate offsets). WGTs is
// wave-private LDS (4KB). Waves fully independent; MLP hides latency.
__global__ __launch_bounds__(256, 2) void fused_attn(
        const float* __restrict__ feat, const float* __restrict__ hid,
        const float4* __restrict__ cmd, const __bf16* __restrict__ WV,
        const __bf16* __restrict__ WKF, float* __restrict__ out)
{
    __shared__ __bf16 WGTs[16 * 132];         // 4.2 KiB, [f][row], padded
    const int tid  = threadIdx.x;
    const int wid  = tid >> 6, lane = tid & 63;
    const int l5   = lane & 31, hi = lane >> 5;
    const int fl   = l5 & 15;
    const bool low = (l5 < 16);
    const int wrow = (blockIdx.x << 7) + (wid << 5);   // wave's 32 rows

    float l_i[16];
    f32x16 s_acc[2];
#pragma unroll
    for (int r = 0; r < 16; ++r) { l_i[r] = 0.f; s_acc[0][r] = 0.f; s_acc[1][r] = 0.f; }

    for (int h = 0; h < 2; ++h) {
        const float* X = h ? hid : feat;

        // ---- A fragments (32x32x16): row wrow+l5, k = u*16 + hi*8 + j ----
        bf16x8 a2[16];
#pragma unroll
        for (int u = 0; u < 16; ++u) {
            const float* p = X + ((size_t)(wrow + l5) << 8) + u * 16 + hi * 8;
            float4 x0 = *(const float4*)p;
            float4 x1 = *(const float4*)(p + 4);
            a2[u] = (bf16x8){ (__bf16)x0.x, (__bf16)x0.y, (__bf16)x0.z, (__bf16)x0.w,
                              (__bf16)x1.x, (__bf16)x1.y, (__bf16)x1.z, (__bf16)x1.w };
        }

        // ---- phase 1: scores. B rows n = nt*32+l5 of WKF (96 rows, L2) ----
        // lane reads 16B at (row n, col ks*16 + hi*8): ks*32B imm offsets.
        const __bf16* kp0 = WKF + (((size_t)(h * 96      + l5)) << 8) + hi * 8;
        const __bf16* kp1 = kp0 + (32 << 8);
        const __bf16* kp2 = kp0 + (64 << 8);

        f32x16 acc1[3];
#pragma unroll
        for (int nt = 0; nt < 3; ++nt)
#pragma unroll
            for (int r = 0; r < 16; ++r) acc1[nt][r] = 0.f;
        __builtin_amdgcn_s_setprio(1);
#pragma unroll
        for (int ks = 0; ks < 16; ++ks) {
            acc1[0] = MFMA32(a2[ks], *(const bf16x8*)(kp0 + ks * 16), acc1[0]);
            acc1[1] = MFMA32(a2[ks], *(const bf16x8*)(kp1 + ks * 16), acc1[1]);
            acc1[2] = MFMA32(a2[ks], *(const bf16x8*)(kp2 + ks * 16), acc1[2]);
        }
        __builtin_amdgcn_s_setprio(0);

        // epilogue: combine c-terms, exp, store wgt, accumulate l
#pragma unroll
        for (int g = 0; g < 4; ++g) {
            bf16x4 wv4;
#pragma unroll
            for (int j = 0; j < 4; ++j) {
                const int r = g * 4 + j;
                const int row32 = j + 8 * g + 4 * hi;
                float4 cm = cmd[wrow + row32];
                float e0, e1, t0[3], t1[3];
#pragma unroll
                for (int nt = 0; nt < 3; ++nt) {
                    e0 = acc1[nt][r];
                    e1 = __shfl_xor(e0, 16);
                    t0[nt] = low ? e0 : e1;
                    t1[nt] = low ? e1 : e0;
                }
                float sc = t0[0] + cm.x * t1[0] + cm.y * t0[1]
                                 + cm.z * t1[1] + cm.w * t0[2];
                float w = __expf(sc);
                wv4[j] = (__bf16)w;
                float ws = w;
                ws += __shfl_xor(ws, 1); ws += __shfl_xor(ws, 2);
                ws += __shfl_xor(ws, 4); ws += __shfl_xor(ws, 8);
                l_i[r] += ws;
            }
            if (low) *(bf16x4*)&WGTs[fl * 132 + (wid << 5) + 8 * g + 4 * hi] = wv4;
        }
        // WGTs write->read is wave-private (same wid stripe): no barrier needed.

        // ---- phase 2: 16 V tiles; B rows f2*64 + nt*32 + l5 of WV (L2) ----
        for (int f2 = 0; f2 < 16; ++f2) {
            const __bf16* vp0 = WV + (((size_t)(h * 1024 + f2 * 64 + l5)) << 8) + hi * 8;
            const __bf16* vp1 = vp0 + (32 << 8);
            f32x16 acc2[2];
#pragma unroll
            for (int r = 0; r < 16; ++r) { acc2[0][r] = 0.f; acc2[1][r] = 0.f; }
            __builtin_amdgcn_s_setprio(1);
#pragma unroll
            for (int ks = 0; ks < 16; ++ks) {
                acc2[0] = MFMA32(a2[ks], *(const bf16x8*)(vp0 + ks * 16), acc2[0]);
                acc2[1] = MFMA32(a2[ks], *(const bf16x8*)(vp1 + ks * 16), acc2[1]);
            }
            __builtin_amdgcn_s_setprio(0);
#pragma unroll
            for (int g = 0; g < 4; ++g) {
                bf16x4 wv = *(const bf16x4*)&WGTs[f2 * 132 + (wid << 5) + 8 * g + 4 * hi];
#pragma unroll
                for (int j = 0; j < 4; ++j) {
                    float w = (float)wv[j];
                    s_acc[0][g * 4 + j] += w * acc2[0][g * 4 + j];
                    s_acc[1][g * 4 + j] += w * acc2[1][g * 4 + j];
                }
            }
        }
    }

    // ---- epilogue: divide by l, store ----
#pragma unroll
    for (int g = 0; g < 4; ++g)
#pragma unroll
        for (int j = 0; j < 4; ++j) {
            const int r = g * 4 + j;
            float inv = 1.0f / l_i[r];
            size_t row = (size_t)(wrow + j + 8 * g + 4 * hi);
            out[(row << 6) + l5]      = s_acc[0][r] * inv;
            out[(row << 6) + 32 + l5] = s_acc[1][r] * inv;
        }
}

// ---------------------------------------------------------------------------
extern "C" void kernel_launch(void* const* d_in, const int* in_sizes, int n_in,
                              void* d_out, int out_size, void* d_ws, size_t ws_size,
                              hipStream_t stream)
{
    (void)in_sizes; (void)n_in; (void)out_size; (void)ws_size;
    const float* feature = (const float*)d_in[0];
    const float* hidden  = (const float*)d_in[1];
    const float* command = (const float*)d_in[2];
    const float* Wq      = (const float*)d_in[3];
    const float* Wkz     = (const float*)d_in[4];
    const float* Wkh     = (const float*)d_in[5];
    const float* Wvz     = (const float*)d_in[6];
    const float* Wvh     = (const float*)d_in[7];
    const float* gammaQ  = (const float*)d_in[8];
    const float* betaQ   = (const float*)d_in[9];
    const float* gammaK  = (const float*)d_in[10];
    const float* betaK   = (const float*)d_in[11];

    char* ws = (char*)d_ws;
    __bf16* WV   = (__bf16*)(ws + WS_WV);
    __bf16* WKF  = (__bf16*)(ws + WS_WKF);
    float*  G    = (float*)(ws + WS_G);
    float*  CS   = (float*)(ws + WS_CS);
    float*  CMDP = (float*)(ws + WS_CMDP);
    float*  Tj   = (float*)(ws + WS_T);
    float*  Uj   = (float*)(ws + WS_U);
    float*  Wq2  = (float*)(ws + WS_WQ2);
    float*  C0   = (float*)(ws + WS_C0);
    float*  outp = (float*)d_out;
    __bf16* Gp   = (__bf16*)d_out;            // 16 MB scratch before final write

    hipMemsetAsync(ws + WS_CS, 0, 0x800, stream);
    setup1<<<416, 512, 0, stream>>>(feature, hidden, (const float4*)command,
                                    Wvz, Wvh, WV, CMDP, CS, Gp);
    gram_reduce<<<512, 256, 0, stream>>>(Gp, G);
    rowstats<<<256, 256, 0, stream>>>(Wkz, Wkh, G, CS, Tj, Uj);
    finalize_kernel<<<1, 64, 0, stream>>>(Wq, gammaQ, betaQ, gammaK, betaK,
                                          CMDP, Tj, Uj, Wq2, C0);
    foldK<<<192, 256, 0, stream>>>(Wkz, Wkh, Wq2, C0, WKF);
    fused_attn<<<512, 256, 0, stream>>>(feature, hidden, (const float4*)command,
                                        WV, WKF, outp);
}

// Round 6
// 338.260 us; speedup vs baseline: 1.8305x; 1.4818x over previous
//
#include <hip/hip_runtime.h>
#include <hip/hip_bf16.h>
#include <math.h>

// ---------------------------------------------------------------------------
// FeatureAttnNet v10 for MI355X (gfx950)
//
// score[b,f] = Y0[b,f] + sum_c cmd[b,c]*Yc[b,f], Y = X @ WKfold^T (BN folded,
// additive BN term cancels in softmax). V GEMM fused with softmax weights.
// v10 = v7 structure (best measured: 134us, bank conflicts 0) + spill fix:
//   phase 1 split into two passes (nt{0,1} fold -> sc[16], then nt{2} + exp)
//   so the peak live set drops from ~200+ regs (a2 64 + acc1 48 + s_acc 32 +
//   l_i 16 + epilogue temps) to ~165. v7's 93MB scratch WRITE came from this
//   peak; spill reloads inside the MFMA cluster drain vmcnt (ordered) and
//   serialize the async gl_lds pipeline (9.5K cyc/phase vs ~600 work).
//   v9 (L2-direct B) REFUTED: 305us, VMEM-latency bound. LDS staging stays.
// setup1 gram: dbuf LDS (2x20KB) + 2-deep register prefetch, 1 barrier/iter.
// Gram: NO atomics — bf16 partials in d_out (scratch before final write).
// ---------------------------------------------------------------------------

typedef float  f32x4   __attribute__((ext_vector_type(4)));
typedef float  f32x16  __attribute__((ext_vector_type(16)));
typedef __bf16 bf16x4  __attribute__((ext_vector_type(4)));
typedef __bf16 bf16x8  __attribute__((ext_vector_type(8)));

#define MFMA16(A, B, C) __builtin_amdgcn_mfma_f32_16x16x32_bf16((A), (B), (C), 0, 0, 0)
#define MFMA32(A, B, C) __builtin_amdgcn_mfma_f32_32x32x16_bf16((A), (B), (C), 0, 0, 0)

#define EPSV 1e-5f

// ---- workspace layout (bytes) ----
#define WS_WV    0x000000u   // 2048*256 bf16 = 1 MiB  [Wvz;Wvh]
#define WS_WKF   0x100000u   // 2*96*256 bf16 = 96 KiB folded K weights (zero-padded)
#define WS_G     0x120000u   // 2*256*256 f32 = 512 KiB
#define WS_CS    0x1A0000u   // 2*256 f32 colsums (zeroed)
#define WS_CMDP  0x1A0800u   // 32*14 f32 cmd partials
#define WS_T     0x1A1800u   // 2048 f32
#define WS_U     0x1A3800u   // 2048 f32
#define WS_WQ2   0x1A5800u   // 256 f32
#define WS_C0    0x1A5C00u   // 64 f32

// async global->LDS, 16B per lane; LDS dest is wave-uniform base + lane*16.
__device__ __forceinline__ void gl_lds16(const void* g, void* l)
{
    __builtin_amdgcn_global_load_lds(
        (const __attribute__((address_space(1))) unsigned int*)g,
        (__attribute__((address_space(3))) unsigned int*)l, 16, 0, 0);
}

// ---------------------------------------------------------------------------
// setup1: blk<128 -> gram partials (bf16 -> d_out); 128..383 -> prepV;
// 384..415 -> cmd stats.
__global__ __launch_bounds__(512, 2) void setup1(const float* __restrict__ feat,
        const float* __restrict__ hid, const float4* __restrict__ cmd,
        const float* __restrict__ Wvz, const float* __restrict__ Wvh,
        __bf16* __restrict__ WV, float* __restrict__ CMDP, float* __restrict__ CS,
        __bf16* __restrict__ Gp)
{
    __shared__ __bf16 T[2 * 256 * 40];        // 40 KiB double buffer
    __shared__ float sm[8][14];
    const int blk = blockIdx.x;
    const int tid = threadIdx.x;

    if (blk >= 384) {                     // ---- cmd stats: 32 blocks ----
        const int b2 = blk - 384;
        float v[14];
#pragma unroll
        for (int k = 0; k < 14; ++k) v[k] = 0.f;
#pragma unroll
        for (int i = 0; i < 4; ++i) {
            float4 c = cmd[(b2 * 4 + i) * 512 + tid];
            v[0] += c.x;  v[1] += c.y;  v[2] += c.z;  v[3] += c.w;
            v[4] += c.x*c.x; v[5] += c.x*c.y; v[6] += c.x*c.z; v[7] += c.x*c.w;
            v[8] += c.y*c.y; v[9] += c.y*c.z; v[10] += c.y*c.w;
            v[11] += c.z*c.z; v[12] += c.z*c.w; v[13] += c.w*c.w;
        }
#pragma unroll
        for (int k = 0; k < 14; ++k) {
            float s = v[k];
#pragma unroll
            for (int off = 32; off; off >>= 1) s += __shfl_xor(s, off);
            if ((tid & 63) == 0) sm[tid >> 6][k] = s;
        }
        __syncthreads();
        if (tid < 14) {
            float s = 0.f;
#pragma unroll
            for (int w = 0; w < 8; ++w) s += sm[w][tid];
            CMDP[b2 * 14 + tid] = s;
        }
        return;
    }
    if (blk >= 128) {                     // ---- prepV: 256 blocks ----
        int t = (blk - 128) * 512 + tid;
        int e = t * 4;
        const float* src = (e < 262144) ? (Wvz + e) : (Wvh + (e - 262144));
        float4 a = *(const float4*)src;
        bf16x4 vv = { (__bf16)a.x, (__bf16)a.y, (__bf16)a.z, (__bf16)a.w };
        *(bf16x4*)(WV + e) = vv;
        return;
    }

    // ---- gram: 128 blocks = 2 mats x 64 chunks x 1024 rows ----
    // Pipelined: T dbuf, 2-deep reg prefetch, 1 barrier per 32-row step.
    const int mat  = blk >> 6;
    const int chunk = blk & 63;
    const float* X = mat ? hid : feat;
    float* cs = CS + mat * 256;
    const int k0   = chunk * 1024;
    const int wid  = tid >> 6, lane = tid & 63, quad = lane >> 4, l15 = lane & 15;
    const int c    = tid & 255;
    const int t8   = tid >> 8;

    f32x4 acc[2][16];
#pragma unroll
    for (int mt = 0; mt < 2; ++mt)
#pragma unroll
        for (int nt = 0; nt < 16; ++nt) acc[mt][nt] = (f32x4){0.f, 0.f, 0.f, 0.f};

    const float* Xc = X + (size_t)k0 * 256 + c;   // element (k, c) at Xc[k*256]
    float ra[16], rb[16];
    float clsum = 0.f;

#define GRAM_LOAD(R, IT) do { \
        const float* p_ = Xc + (size_t)(IT) * 32 * 256; \
        _Pragma("unroll") \
        for (int i_ = 0; i_ < 16; ++i_) (R)[i_] = p_[(size_t)(t8 + 2 * i_) * 256]; \
    } while (0)
#define GRAM_WRITE(R, BUFO) do { \
        _Pragma("unroll") \
        for (int i_ = 0; i_ < 16; ++i_) { \
            float x_ = (R)[i_]; clsum += x_; \
            T[(BUFO) + c * 40 + t8 + 2 * i_] = (__bf16)x_; } \
    } while (0)
#define GRAM_MFMA(BUFO) do { \
        const __bf16* Tb_ = &T[(BUFO)]; \
        bf16x8 a0_ = *(const bf16x8*)&Tb_[(wid * 32 +      l15) * 40 + quad * 8]; \
        bf16x8 a1_ = *(const bf16x8*)&Tb_[(wid * 32 + 16 + l15) * 40 + quad * 8]; \
        _Pragma("unroll") \
        for (int nt_ = 0; nt_ < 16; ++nt_) { \
            bf16x8 b_ = *(const bf16x8*)&Tb_[(nt_ * 16 + l15) * 40 + quad * 8]; \
            acc[0][nt_] = MFMA16(a0_, b_, acc[0][nt_]); \
            acc[1][nt_] = MFMA16(a1_, b_, acc[1][nt_]); } \
    } while (0)

    GRAM_LOAD(ra, 0);                     // it0
    GRAM_LOAD(rb, 1);                     // it1
    GRAM_WRITE(ra, 0);                    // it0 -> T0
    GRAM_LOAD(ra, 2);                     // it2 (consumed body B of it2=0)
    __syncthreads();

    for (int it2 = 0; it2 < 16; ++it2) {
        // body A: write rb (it 2*it2+1) -> T1; refill rb <- it 2*it2+3; MFMA T0
        GRAM_WRITE(rb, 10240);
        if (it2 < 15) GRAM_LOAD(rb, 2 * it2 + 3);
        GRAM_MFMA(0);
        __syncthreads();
        // body B: write ra (it 2*it2+2) -> T0; refill ra <- it 2*it2+4; MFMA T1
        if (it2 < 15) {
            GRAM_WRITE(ra, 0);
            if (it2 < 14) GRAM_LOAD(ra, 2 * it2 + 4);
        }
        GRAM_MFMA(10240);
        __syncthreads();
    }
#undef GRAM_LOAD
#undef GRAM_WRITE
#undef GRAM_MFMA

    atomicAdd(&cs[c], clsum);             // 512 addrs, 128-way — cheap
    __bf16* outp = Gp + (size_t)blk * 65536;
#pragma unroll
    for (int mt = 0; mt < 2; ++mt)
#pragma unroll
        for (int nt = 0; nt < 16; ++nt)
#pragma unroll
            for (int r = 0; r < 4; ++r) {
                int gi = wid * 32 + mt * 16 + quad * 4 + r;
                int gj = nt * 16 + l15;
                outp[gi * 256 + gj] = (__bf16)acc[mt][nt][r];
            }
}

// ---------------------------------------------------------------------------
__global__ void gram_reduce(const __bf16* __restrict__ Gp, float* __restrict__ G)
{
    int o = blockIdx.x * 256 + threadIdx.x;      // 512 x 256 = 131072
    int mat = o >> 16, e = o & 65535;
    const __bf16* p = Gp + (size_t)mat * 64 * 65536 + e;
    float s = 0.f;
#pragma unroll 8
    for (int c = 0; c < 64; ++c) s += (float)p[(size_t)c * 65536];
    G[o] = s;
}

// ---------------------------------------------------------------------------
__global__ void rowstats(const float* __restrict__ Wkz, const float* __restrict__ Wkh,
        const float* __restrict__ G, const float* __restrict__ CS,
        float* __restrict__ Tout, float* __restrict__ Uout)
{
    const int blk = blockIdx.x;               // 256 blocks
    const int mat = blk >> 7, jg = blk & 127;
    const float* Wsrc = (mat ? Wkh : Wkz) + (size_t)jg * 8 * 256;
    const float* Gm = G + (size_t)mat * 65536;
    const float* cs = CS + mat * 256;
    __shared__ float wlT[256 * 8];
    __shared__ float red[4][16];
    const int tid = threadIdx.x, wid = tid >> 6, lane = tid & 63;
#pragma unroll
    for (int jj = 0; jj < 8; ++jj) wlT[tid * 8 + jj] = Wsrc[jj * 256 + tid];
    __syncthreads();
    float inner[8];
#pragma unroll
    for (int jj = 0; jj < 8; ++jj) inner[jj] = 0.f;
    for (int r = 0; r < 256; ++r) {
        float g = Gm[r * 256 + tid];
        float4 w0 = *(const float4*)&wlT[r * 8];
        float4 w1 = *(const float4*)&wlT[r * 8 + 4];
        inner[0] = fmaf(w0.x, g, inner[0]); inner[1] = fmaf(w0.y, g, inner[1]);
        inner[2] = fmaf(w0.z, g, inner[2]); inner[3] = fmaf(w0.w, g, inner[3]);
        inner[4] = fmaf(w1.x, g, inner[4]); inner[5] = fmaf(w1.y, g, inner[5]);
        inner[6] = fmaf(w1.z, g, inner[6]); inner[7] = fmaf(w1.w, g, inner[7]);
    }
    float cst = cs[tid];
#pragma unroll
    for (int jj = 0; jj < 8; ++jj) {
        float wme = wlT[tid * 8 + jj];
        float p = wme * inner[jj];
        float u = wme * cst;
#pragma unroll
        for (int off = 32; off; off >>= 1) { p += __shfl_xor(p, off); u += __shfl_xor(u, off); }
        if (lane == 0) { red[wid][jj] = p; red[wid][jj + 8] = u; }
    }
    __syncthreads();
    if (tid < 16) {
        float s = red[0][tid] + red[1][tid] + red[2][tid] + red[3][tid];
        int jj = tid & 7;
        int j = mat * 1024 + jg * 8 + jj;
        if (tid < 8) Tout[j] = s; else Uout[j] = s;
    }
}

// ---------------------------------------------------------------------------
__global__ void finalize_kernel(const float* __restrict__ Wq,
        const float* __restrict__ gQ, const float* __restrict__ bQ,
        const float* __restrict__ gK, const float* __restrict__ bK,
        const float* __restrict__ CMDP, const float* __restrict__ T,
        const float* __restrict__ U, float* __restrict__ Wq2, float* __restrict__ C0)
{
    __shared__ float s14[14];
    const int d = threadIdx.x;
    if (d < 14) {
        float s = 0.f;
        for (int b = 0; b < 32; ++b) s += CMDP[b * 14 + d];
        s14[d] = s;
    }
    __syncthreads();
    float s4[4] = { s14[0], s14[1], s14[2], s14[3] };
    float gc[4][4];
    gc[0][0] = s14[4];
    gc[0][1] = gc[1][0] = s14[5];
    gc[0][2] = gc[2][0] = s14[6];
    gc[0][3] = gc[3][0] = s14[7];
    gc[1][1] = s14[8];
    gc[1][2] = gc[2][1] = s14[9];
    gc[1][3] = gc[3][1] = s14[10];
    gc[2][2] = s14[11];
    gc[2][3] = gc[3][2] = s14[12];
    gc[3][3] = s14[13];
    float wq[4];
#pragma unroll
    for (int c = 0; c < 4; ++c) wq[c] = Wq[d * 4 + c];
    const float invB = 1.0f / 65536.0f;
    float mQ = (wq[0]*s4[0] + wq[1]*s4[1] + wq[2]*s4[2] + wq[3]*s4[3]) * invB;
    float eq2 = 0.f;
#pragma unroll
    for (int c = 0; c < 4; ++c)
#pragma unroll
        for (int c2 = 0; c2 < 4; ++c2) eq2 += wq[c] * wq[c2] * gc[c][c2];
    eq2 *= invB;
    float vQ  = eq2 - mQ * mQ;
    float aQ  = gQ[d] / sqrtf(vQ + EPSV);
    float bQv = bQ[d] - mQ * aQ;
    float S2 = 0.f, S1 = 0.f;
#pragma unroll
    for (int f = 0; f < 32; ++f) { S2 += T[f * 64 + d]; S1 += U[f * 64 + d]; }
    const float invBF = 1.0f / (65536.0f * 32.0f);
    float e2 = S2 * invBF, mK = S1 * invBF;
    float vK = e2 - mK * mK;
    float aK = gK[d] / sqrtf(vK + EPSV);
    float c1 = aQ * aK * 0.125f;      // 1/sqrt(64) folded in
    C0[d] = bQv * aK * 0.125f;
#pragma unroll
    for (int c = 0; c < 4; ++c) Wq2[d * 4 + c] = c1 * wq[c];
}

// ---------------------------------------------------------------------------
// WKF[h][r = c*16 + fl][k] = sum_d coef_c[d]*W_h[fl*64+d][k]; rows 80..95 = 0.
__global__ void foldK(const float* __restrict__ Wkz, const float* __restrict__ Wkh,
                      const float* __restrict__ Wq2, const float* __restrict__ C0,
                      __bf16* __restrict__ WKF)
{
    const int blk = blockIdx.x;               // 192
    const int h = blk / 96, rr = blk % 96;
    const int k = threadIdx.x;
    float s = 0.f;
    if (rr < 80) {
        const int c = rr >> 4, fl = rr & 15;
        const float* Wsrc = (h ? Wkh : Wkz) + (size_t)fl * 64 * 256;
        for (int d = 0; d < 64; ++d) {
            float coef = (c == 0) ? C0[d] : Wq2[d * 4 + (c - 1)];
            s = fmaf(coef, Wsrc[d * 256 + k], s);
        }
    }
    WKF[(size_t)(h * 96 + rr) * 256 + k] = (__bf16)s;
}

// ---------------------------------------------------------------------------
// fused_attn v10: 512 blocks x 256 threads; wave = 32 rows; B staged via
// global_load_lds (linear LDS dest, pre-swizzled global src, q^(n&31) full
// swizzle = conflict-free, verified R3); dbuf V tiles, 1 barrier per tile;
// X read once. Phase 1 split into two passes to cap the register peak
// (spill fix): pass A nt{0,1} -> fold into sc[16]; pass B nt{2} -> exp.
__global__ __launch_bounds__(256, 2) void fused_attn(
        const float* __restrict__ feat, const float* __restrict__ hid,
        const float4* __restrict__ cmd, const __bf16* __restrict__ WV,
        const __bf16* __restrict__ WKF, float* __restrict__ out)
{
    __shared__ __bf16 BUF[32768];             // 64 KiB (dbuf 2x32KB / p1 48KB)
    __shared__ __bf16 WGTs[16 * 132];         // [f][row], stride 132 (bank pad)
    const int tid  = threadIdx.x;
    const int wid  = tid >> 6, lane = tid & 63;
    const int l5   = lane & 31, hi = lane >> 5;
    const int fl   = l5 & 15;
    const bool low = (l5 < 16);
    const int wrow = (blockIdx.x << 7) + (wid << 5);   // wave's 32 rows

    // Staging chunk i (per wave): rows n = wid*2 + i*8 + hi, 64 lanes x 16B =
    // 1KiB linear LDS at elem (wid*2+i*8)*256. Source slot pre-swizzled:
    // BUF[n*256 + s*8..] = SRC[n*256 + (s^(n&31))*8..]. Read at slot
    // q^(n&31) returns SRC slot q. 32 lanes -> 32 distinct slots: conflict-free.
#define STAGE_CHUNK(SRC, DSTBASE, I) do { \
        int n_ = (wid << 1) + ((I) << 3) + hi; \
        gl_lds16((SRC) + n_ * 256 + ((l5 ^ (n_ & 31)) << 3), \
                 &BUF[(DSTBASE) + (((wid << 1) + ((I) << 3)) << 8)]); \
    } while (0)

    float l_i[16];
    f32x16 s_acc[2];
#pragma unroll
    for (int r = 0; r < 16; ++r) { l_i[r] = 0.f; s_acc[0][r] = 0.f; s_acc[1][r] = 0.f; }

    for (int h = 0; h < 2; ++h) {
        const float* X = h ? hid : feat;
        const __bf16* Wkf = WKF + ((size_t)h * 96 << 8);

        // ---- A fragments (32x32x16): row wrow+l5, k = u*16 + hi*8 + j ----
        bf16x8 a2[16];
#pragma unroll
        for (int u = 0; u < 16; ++u) {
            const float* p = X + ((size_t)(wrow + l5) << 8) + u * 16 + hi * 8;
            float4 x0 = *(const float4*)p;
            float4 x1 = *(const float4*)(p + 4);
            a2[u] = (bf16x8){ (__bf16)x0.x, (__bf16)x0.y, (__bf16)x0.z, (__bf16)x0.w,
                              (__bf16)x1.x, (__bf16)x1.y, (__bf16)x1.z, (__bf16)x1.w };
        }

        // ---- phase 1: stage WKF (96 rows, 48KB); scores in two passes ----
        __syncthreads();                      // prior readers of BUF done
#pragma unroll
        for (int i = 0; i < 12; ++i)
            STAGE_CHUNK(Wkf, 0, i);
        __syncthreads();                      // barrier drain waits staging

        float sc[16];
        // pass A: nt = 0,1 -> fold c-terms {1, cmd.x, cmd.y, cmd.z} into sc
        {
            f32x16 accA, accB;
#pragma unroll
            for (int r = 0; r < 16; ++r) { accA[r] = 0.f; accB[r] = 0.f; }
            __builtin_amdgcn_s_setprio(1);
#pragma unroll
            for (int ks = 0; ks < 16; ++ks) {
                {
                    int n = l5;
                    bf16x8 b = *(const bf16x8*)&BUF[n * 256 + (((ks * 2 + hi) ^ (n & 31)) << 3)];
                    accA = MFMA32(a2[ks], b, accA);
                }
                {
                    int n = 32 + l5;
                    bf16x8 b = *(const bf16x8*)&BUF[n * 256 + (((ks * 2 + hi) ^ (n & 31)) << 3)];
                    accB = MFMA32(a2[ks], b, accB);
                }
            }
            __builtin_amdgcn_s_setprio(0);
#pragma unroll
            for (int g = 0; g < 4; ++g)
#pragma unroll
                for (int j = 0; j < 4; ++j) {
                    const int r = g * 4 + j;
                    float4 cm = cmd[wrow + j + 8 * g + 4 * hi];
                    float e0 = accA[r], e1 = __shfl_xor(e0, 16);
                    float t00 = low ? e0 : e1, t10 = low ? e1 : e0;
                    float f0 = accB[r], f1 = __shfl_xor(f0, 16);
                    float t01 = low ? f0 : f1, t11 = low ? f1 : f0;
                    sc[r] = t00 + cm.x * t10 + cm.y * t01 + cm.z * t11;
                }
        }
        // pass B: nt = 2 -> + cmd.w term, exp, store weights, accumulate l
        {
            f32x16 accC;
#pragma unroll
            for (int r = 0; r < 16; ++r) accC[r] = 0.f;
            __builtin_amdgcn_s_setprio(1);
#pragma unroll
            for (int ks = 0; ks < 16; ++ks) {
                int n = 64 + l5;
                bf16x8 b = *(const bf16x8*)&BUF[n * 256 + (((ks * 2 + hi) ^ (n & 31)) << 3)];
                accC = MFMA32(a2[ks], b, accC);
            }
            __builtin_amdgcn_s_setprio(0);
#pragma unroll
            for (int g = 0; g < 4; ++g) {
                bf16x4 wv4;
#pragma unroll
                for (int j = 0; j < 4; ++j) {
                    const int r = g * 4 + j;
                    float4 cm = cmd[wrow + j + 8 * g + 4 * hi];
                    float e0 = accC[r], e1 = __shfl_xor(e0, 16);
                    float t0 = low ? e0 : e1;              // t1 = zero padding
                    float w = __expf(sc[r] + cm.w * t0);
                    wv4[j] = (__bf16)w;
                    float ws = w;
                    ws += __shfl_xor(ws, 1); ws += __shfl_xor(ws, 2);
                    ws += __shfl_xor(ws, 4); ws += __shfl_xor(ws, 8);
                    l_i[r] += ws;
                }
                if (low) *(bf16x4*)&WGTs[fl * 132 + (wid << 5) + 8 * g + 4 * hi] = wv4;
            }
        }

        __syncthreads();                      // phase-1 BUF reads done

        // first V tile of this half -> buf0 (cold once per half; L2-resident)
        {
            const __bf16* base = WV + ((size_t)(h * 16) << 14);
#pragma unroll
            for (int i = 0; i < 8; ++i)
                STAGE_CHUNK(base, 0, i);
        }

        // ---- phase 2: 16 V tiles, dbuf, 1 barrier each ----
        for (int f2 = 0; f2 < 16; ++f2) {
            const int bufsel = (f2 & 1) << 14;
            __syncthreads();                  // drains cur staging; ends prev reads
            if (f2 < 15) {                    // prefetch next tile into other buf
                const __bf16* base = WV + ((size_t)(h * 16 + f2 + 1) << 14);
                const int nsel = bufsel ^ 16384;
#pragma unroll
                for (int i = 0; i < 8; ++i)
                    STAGE_CHUNK(base, nsel, i);
            }
            __builtin_amdgcn_sched_barrier(0);   // pin prefetch-issue before MFMAs
            f32x16 acc2[2];
#pragma unroll
            for (int r = 0; r < 16; ++r) { acc2[0][r] = 0.f; acc2[1][r] = 0.f; }
            __builtin_amdgcn_s_setprio(1);
#pragma unroll
            for (int ks = 0; ks < 16; ++ks)
#pragma unroll
                for (int nt = 0; nt < 2; ++nt) {
                    int n = nt * 32 + l5;
                    bf16x8 b = *(const bf16x8*)&BUF[bufsel + n * 256
                                                    + (((ks * 2 + hi) ^ (n & 31)) << 3)];
                    acc2[nt] = MFMA32(a2[ks], b, acc2[nt]);
                }
            __builtin_amdgcn_s_setprio(0);
#pragma unroll
            for (int g = 0; g < 4; ++g) {
                bf16x4 wv = *(const bf16x4*)&WGTs[f2 * 132 + (wid << 5) + 8 * g + 4 * hi];
#pragma unroll
                for (int j = 0; j < 4; ++j) {
                    float w = (float)wv[j];
                    s_acc[0][g * 4 + j] += w * acc2[0][g * 4 + j];
                    s_acc[1][g * 4 + j] += w * acc2[1][g * 4 + j];
                }
            }
        }
    }
#undef STAGE_CHUNK

    // ---- epilogue: divide by l, store ----
#pragma unroll
    for (int g = 0; g < 4; ++g)
#pragma unroll
        for (int j = 0; j < 4; ++j) {
            const int r = g * 4 + j;
            float inv = 1.0f / l_i[r];
            size_t row = (size_t)(wrow + j + 8 * g + 4 * hi);
            out[(row << 6) + l5]      = s_acc[0][r] * inv;
            out[(row << 6) + 32 + l5] = s_acc[1][r] * inv;
        }
}

// ---------------------------------------------------------------------------
extern "C" void kernel_launch(void* const* d_in, const int* in_sizes, int n_in,
                              void* d_out, int out_size, void* d_ws, size_t ws_size,
                              hipStream_t stream)
{
    (void)in_sizes; (void)n_in; (void)out_size; (void)ws_size;
    const float* feature = (const float*)d_in[0];
    const float* hidden  = (const float*)d_in[1];
    const float* command = (const float*)d_in[2];
    const float* Wq      = (const float*)d_in[3];
    const float* Wkz     = (const float*)d_in[4];
    const float* Wkh     = (const float*)d_in[5];
    const float* Wvz     = (const float*)d_in[6];
    const float* Wvh     = (const float*)d_in[7];
    const float* gammaQ  = (const float*)d_in[8];
    const float* betaQ   = (const float*)d_in[9];
    const float* gammaK  = (const float*)d_in[10];
    const float* betaK   = (const float*)d_in[11];

    char* ws = (char*)d_ws;
    __bf16* WV   = (__bf16*)(ws + WS_WV);
    __bf16* WKF  = (__bf16*)(ws + WS_WKF);
    float*  G    = (float*)(ws + WS_G);
    float*  CS   = (float*)(ws + WS_CS);
    float*  CMDP = (float*)(ws + WS_CMDP);
    float*  Tj   = (float*)(ws + WS_T);
    float*  Uj   = (float*)(ws + WS_U);
    float*  Wq2  = (float*)(ws + WS_WQ2);
    float*  C0   = (float*)(ws + WS_C0);
    float*  outp = (float*)d_out;
    __bf16* Gp   = (__bf16*)d_out;            // 16 MB scratch before final write

    hipMemsetAsync(ws + WS_CS, 0, 0x800, stream);
    setup1<<<416, 512, 0, stream>>>(feature, hidden, (const float4*)command,
                                    Wvz, Wvh, WV, CMDP, CS, Gp);
    gram_reduce<<<512, 256, 0, stream>>>(Gp, G);
    rowstats<<<256, 256, 0, stream>>>(Wkz, Wkh, G, CS, Tj, Uj);
    finalize_kernel<<<1, 64, 0, stream>>>(Wq, gammaQ, betaQ, gammaK, betaK,
                                          CMDP, Tj, Uj, Wq2, C0);
    foldK<<<192, 256, 0, stream>>>(Wkz, Wkh, Wq2, C0, WKF);
    fused_attn<<<512, 256, 0, stream>>>(feature, hidden, (const float4*)command,
                                        WV, WKF, outp);
}

// Round 7
// 322.768 us; speedup vs baseline: 1.9184x; 1.0480x over previous
//
#include <hip/hip_runtime.h>
#include <hip/hip_bf16.h>
#include <math.h>

// ---------------------------------------------------------------------------
// FeatureAttnNet v11 for MI355X (gfx950)
//
// score[b,f] = Y0[b,f] + sum_c cmd[b,c]*Yc[b,f], Y = X @ WKfold^T (BN folded,
// additive BN term cancels in softmax). V GEMM fused with softmax weights.
// v11 = v7 base (134us best; phase-1 acc1[3] single pass restored — v10's
//   split REFUTED: WRITE +11MB, dur +10us) with phase-2 re-scheduled as
//   T3/T4 counted-vmcnt: raw s_barrier + s_waitcnt vmcnt(8) (never 0 in the
//   main loop), prefetch issued BEFORE the barrier, second pure s_barrier
//   closes the WAR window. No full vmcnt(0)+lgkmcnt(0) drains per tile.
// setup1 gram: k = 16*t8+i mapping -> bf16x4 LDS writes (4x fewer ds_write).
// finalize folded redundantly into foldK (one launch less).
// Gram: NO atomics — bf16 partials in d_out (scratch before final write).
// ---------------------------------------------------------------------------

typedef float  f32x4   __attribute__((ext_vector_type(4)));
typedef float  f32x16  __attribute__((ext_vector_type(16)));
typedef __bf16 bf16x4  __attribute__((ext_vector_type(4)));
typedef __bf16 bf16x8  __attribute__((ext_vector_type(8)));

#define MFMA16(A, B, C) __builtin_amdgcn_mfma_f32_16x16x32_bf16((A), (B), (C), 0, 0, 0)
#define MFMA32(A, B, C) __builtin_amdgcn_mfma_f32_32x32x16_bf16((A), (B), (C), 0, 0, 0)

#define EPSV 1e-5f

// ---- workspace layout (bytes) ----
#define WS_WV    0x000000u   // 2048*256 bf16 = 1 MiB  [Wvz;Wvh]
#define WS_WKF   0x100000u   // 2*96*256 bf16 = 96 KiB folded K weights (zero-padded)
#define WS_G     0x120000u   // 2*256*256 f32 = 512 KiB
#define WS_CS    0x1A0000u   // 2*256 f32 colsums (zeroed)
#define WS_CMDP  0x1A0800u   // 32*14 f32 cmd partials
#define WS_T     0x1A1800u   // 2048 f32
#define WS_U     0x1A3800u   // 2048 f32

// async global->LDS, 16B per lane; LDS dest is wave-uniform base + lane*16.
__device__ __forceinline__ void gl_lds16(const void* g, void* l)
{
    __builtin_amdgcn_global_load_lds(
        (const __attribute__((address_space(1))) unsigned int*)g,
        (__attribute__((address_space(3))) unsigned int*)l, 16, 0, 0);
}

// ---------------------------------------------------------------------------
// setup1: blk<128 -> gram partials (bf16 -> d_out); 128..383 -> prepV;
// 384..415 -> cmd stats.
__global__ __launch_bounds__(512, 2) void setup1(const float* __restrict__ feat,
        const float* __restrict__ hid, const float4* __restrict__ cmd,
        const float* __restrict__ Wvz, const float* __restrict__ Wvh,
        __bf16* __restrict__ WV, float* __restrict__ CMDP, float* __restrict__ CS,
        __bf16* __restrict__ Gp)
{
    __shared__ __bf16 T[2 * 256 * 40];        // 40 KiB double buffer
    __shared__ float sm[8][14];
    const int blk = blockIdx.x;
    const int tid = threadIdx.x;

    if (blk >= 384) {                     // ---- cmd stats: 32 blocks ----
        const int b2 = blk - 384;
        float v[14];
#pragma unroll
        for (int k = 0; k < 14; ++k) v[k] = 0.f;
#pragma unroll
        for (int i = 0; i < 4; ++i) {
            float4 c = cmd[(b2 * 4 + i) * 512 + tid];
            v[0] += c.x;  v[1] += c.y;  v[2] += c.z;  v[3] += c.w;
            v[4] += c.x*c.x; v[5] += c.x*c.y; v[6] += c.x*c.z; v[7] += c.x*c.w;
            v[8] += c.y*c.y; v[9] += c.y*c.z; v[10] += c.y*c.w;
            v[11] += c.z*c.z; v[12] += c.z*c.w; v[13] += c.w*c.w;
        }
#pragma unroll
        for (int k = 0; k < 14; ++k) {
            float s = v[k];
#pragma unroll
            for (int off = 32; off; off >>= 1) s += __shfl_xor(s, off);
            if ((tid & 63) == 0) sm[tid >> 6][k] = s;
        }
        __syncthreads();
        if (tid < 14) {
            float s = 0.f;
#pragma unroll
            for (int w = 0; w < 8; ++w) s += sm[w][tid];
            CMDP[b2 * 14 + tid] = s;
        }
        return;
    }
    if (blk >= 128) {                     // ---- prepV: 256 blocks ----
        int t = (blk - 128) * 512 + tid;
        int e = t * 4;
        const float* src = (e < 262144) ? (Wvz + e) : (Wvh + (e - 262144));
        float4 a = *(const float4*)src;
        bf16x4 vv = { (__bf16)a.x, (__bf16)a.y, (__bf16)a.z, (__bf16)a.w };
        *(bf16x4*)(WV + e) = vv;
        return;
    }

    // ---- gram: 128 blocks = 2 mats x 64 chunks x 1024 rows ----
    // Pipelined: T dbuf, 2-deep reg prefetch, 1 barrier per 32-row step.
    // k-mapping: thread (c, t8) handles k = 16*t8 + i (contiguous) so LDS
    // writes are 4 x bf16x4 instead of 16 scalar ds_write_b16.
    const int mat  = blk >> 6;
    const int chunk = blk & 63;
    const float* X = mat ? hid : feat;
    float* cs = CS + mat * 256;
    const int k0   = chunk * 1024;
    const int wid  = tid >> 6, lane = tid & 63, quad = lane >> 4, l15 = lane & 15;
    const int c    = tid & 255;
    const int t8   = tid >> 8;

    f32x4 acc[2][16];
#pragma unroll
    for (int mt = 0; mt < 2; ++mt)
#pragma unroll
        for (int nt = 0; nt < 16; ++nt) acc[mt][nt] = (f32x4){0.f, 0.f, 0.f, 0.f};

    const float* Xc = X + (size_t)k0 * 256 + c + (size_t)t8 * 16 * 256;
    float ra[16], rb[16];
    float clsum = 0.f;

#define GRAM_LOAD(R, IT) do { \
        const float* p_ = Xc + (size_t)(IT) * 32 * 256; \
        _Pragma("unroll") \
        for (int i_ = 0; i_ < 16; ++i_) (R)[i_] = p_[(size_t)i_ * 256]; \
    } while (0)
#define GRAM_WRITE(R, BUFO) do { \
        _Pragma("unroll") \
        for (int i2_ = 0; i2_ < 4; ++i2_) { \
            float x0_ = (R)[4*i2_], x1_ = (R)[4*i2_+1]; \
            float x2_ = (R)[4*i2_+2], x3_ = (R)[4*i2_+3]; \
            clsum += x0_ + x1_ + x2_ + x3_; \
            bf16x4 v_ = { (__bf16)x0_, (__bf16)x1_, (__bf16)x2_, (__bf16)x3_ }; \
            *(bf16x4*)&T[(BUFO) + c * 40 + t8 * 16 + i2_ * 4] = v_; } \
    } while (0)
#define GRAM_MFMA(BUFO) do { \
        const __bf16* Tb_ = &T[(BUFO)]; \
        bf16x8 a0_ = *(const bf16x8*)&Tb_[(wid * 32 +      l15) * 40 + quad * 8]; \
        bf16x8 a1_ = *(const bf16x8*)&Tb_[(wid * 32 + 16 + l15) * 40 + quad * 8]; \
        _Pragma("unroll") \
        for (int nt_ = 0; nt_ < 16; ++nt_) { \
            bf16x8 b_ = *(const bf16x8*)&Tb_[(nt_ * 16 + l15) * 40 + quad * 8]; \
            acc[0][nt_] = MFMA16(a0_, b_, acc[0][nt_]); \
            acc[1][nt_] = MFMA16(a1_, b_, acc[1][nt_]); } \
    } while (0)

    GRAM_LOAD(ra, 0);                     // it0
    GRAM_LOAD(rb, 1);                     // it1
    GRAM_WRITE(ra, 0);                    // it0 -> T0
    GRAM_LOAD(ra, 2);                     // it2 (consumed body B of it2=0)
    __syncthreads();

    for (int it2 = 0; it2 < 16; ++it2) {
        // body A: write rb (it 2*it2+1) -> T1; refill rb <- it 2*it2+3; MFMA T0
        GRAM_WRITE(rb, 10240);
        if (it2 < 15) GRAM_LOAD(rb, 2 * it2 + 3);
        GRAM_MFMA(0);
        __syncthreads();
        // body B: write ra (it 2*it2+2) -> T0; refill ra <- it 2*it2+4; MFMA T1
        if (it2 < 15) {
            GRAM_WRITE(ra, 0);
            if (it2 < 14) GRAM_LOAD(ra, 2 * it2 + 4);
        }
        GRAM_MFMA(10240);
        __syncthreads();
    }
#undef GRAM_LOAD
#undef GRAM_WRITE
#undef GRAM_MFMA

    atomicAdd(&cs[c], clsum);             // 512 addrs, 128-way — cheap
    __bf16* outp = Gp + (size_t)blk * 65536;
#pragma unroll
    for (int mt = 0; mt < 2; ++mt)
#pragma unroll
        for (int nt = 0; nt < 16; ++nt)
#pragma unroll
            for (int r = 0; r < 4; ++r) {
                int gi = wid * 32 + mt * 16 + quad * 4 + r;
                int gj = nt * 16 + l15;
                outp[gi * 256 + gj] = (__bf16)acc[mt][nt][r];
            }
}

// ---------------------------------------------------------------------------
__global__ void gram_reduce(const __bf16* __restrict__ Gp, float* __restrict__ G)
{
    int o = blockIdx.x * 256 + threadIdx.x;      // 512 x 256 = 131072
    int mat = o >> 16, e = o & 65535;
    const __bf16* p = Gp + (size_t)mat * 64 * 65536 + e;
    float s = 0.f;
#pragma unroll 8
    for (int c = 0; c < 64; ++c) s += (float)p[(size_t)c * 65536];
    G[o] = s;
}

// ---------------------------------------------------------------------------
__global__ void rowstats(const float* __restrict__ Wkz, const float* __restrict__ Wkh,
        const float* __restrict__ G, const float* __restrict__ CS,
        float* __restrict__ Tout, float* __restrict__ Uout)
{
    const int blk = blockIdx.x;               // 256 blocks
    const int mat = blk >> 7, jg = blk & 127;
    const float* Wsrc = (mat ? Wkh : Wkz) + (size_t)jg * 8 * 256;
    const float* Gm = G + (size_t)mat * 65536;
    const float* cs = CS + mat * 256;
    __shared__ float wlT[256 * 8];
    __shared__ float red[4][16];
    const int tid = threadIdx.x, wid = tid >> 6, lane = tid & 63;
#pragma unroll
    for (int jj = 0; jj < 8; ++jj) wlT[tid * 8 + jj] = Wsrc[jj * 256 + tid];
    __syncthreads();
    float inner[8];
#pragma unroll
    for (int jj = 0; jj < 8; ++jj) inner[jj] = 0.f;
    for (int r = 0; r < 256; ++r) {
        float g = Gm[r * 256 + tid];
        float4 w0 = *(const float4*)&wlT[r * 8];
        float4 w1 = *(const float4*)&wlT[r * 8 + 4];
        inner[0] = fmaf(w0.x, g, inner[0]); inner[1] = fmaf(w0.y, g, inner[1]);
        inner[2] = fmaf(w0.z, g, inner[2]); inner[3] = fmaf(w0.w, g, inner[3]);
        inner[4] = fmaf(w1.x, g, inner[4]); inner[5] = fmaf(w1.y, g, inner[5]);
        inner[6] = fmaf(w1.z, g, inner[6]); inner[7] = fmaf(w1.w, g, inner[7]);
    }
    float cst = cs[tid];
#pragma unroll
    for (int jj = 0; jj < 8; ++jj) {
        float wme = wlT[tid * 8 + jj];
        float p = wme * inner[jj];
        float u = wme * cst;
#pragma unroll
        for (int off = 32; off; off >>= 1) { p += __shfl_xor(p, off); u += __shfl_xor(u, off); }
        if (lane == 0) { red[wid][jj] = p; red[wid][jj + 8] = u; }
    }
    __syncthreads();
    if (tid < 16) {
        float s = red[0][tid] + red[1][tid] + red[2][tid] + red[3][tid];
        int jj = tid & 7;
        int j = mat * 1024 + jg * 8 + jj;
        if (tid < 8) Tout[j] = s; else Uout[j] = s;
    }
}

// ---------------------------------------------------------------------------
// foldK with finalize folded in (each block redundantly computes the tiny
// BN-fold coefficients; removes a serialized 1-block launch).
// WKF[h][r = c*16 + fl][k] = sum_d coef_c[d]*W_h[fl*64+d][k]; rows 80..95 = 0.
__global__ void foldK(const float* __restrict__ Wkz, const float* __restrict__ Wkh,
                      const float* __restrict__ Wq,
                      const float* __restrict__ gQ, const float* __restrict__ bQ,
                      const float* __restrict__ gK, const float* __restrict__ bK,
                      const float* __restrict__ CMDP, const float* __restrict__ T,
                      const float* __restrict__ U, __bf16* __restrict__ WKF)
{
    __shared__ float s14[14];
    __shared__ float sC0[64];
    __shared__ float sWq2[256];
    const int tid = threadIdx.x;
    if (tid < 14) {
        float s = 0.f;
        for (int b = 0; b < 32; ++b) s += CMDP[b * 14 + tid];
        s14[tid] = s;
    }
    __syncthreads();
    if (tid < 64) {
        const int d = tid;
        float s4[4] = { s14[0], s14[1], s14[2], s14[3] };
        float gc[4][4];
        gc[0][0] = s14[4];
        gc[0][1] = gc[1][0] = s14[5];
        gc[0][2] = gc[2][0] = s14[6];
        gc[0][3] = gc[3][0] = s14[7];
        gc[1][1] = s14[8];
        gc[1][2] = gc[2][1] = s14[9];
        gc[1][3] = gc[3][1] = s14[10];
        gc[2][2] = s14[11];
        gc[2][3] = gc[3][2] = s14[12];
        gc[3][3] = s14[13];
        float wq[4];
#pragma unroll
        for (int c = 0; c < 4; ++c) wq[c] = Wq[d * 4 + c];
        const float invB = 1.0f / 65536.0f;
        float mQ = (wq[0]*s4[0] + wq[1]*s4[1] + wq[2]*s4[2] + wq[3]*s4[3]) * invB;
        float eq2 = 0.f;
#pragma unroll
        for (int c = 0; c < 4; ++c)
#pragma unroll
            for (int c2 = 0; c2 < 4; ++c2) eq2 += wq[c] * wq[c2] * gc[c][c2];
        eq2 *= invB;
        float vQ  = eq2 - mQ * mQ;
        float aQ  = gQ[d] / sqrtf(vQ + EPSV);
        float bQv = bQ[d] - mQ * aQ;
        float S2 = 0.f, S1 = 0.f;
#pragma unroll
        for (int f = 0; f < 32; ++f) { S2 += T[f * 64 + d]; S1 += U[f * 64 + d]; }
        const float invBF = 1.0f / (65536.0f * 32.0f);
        float e2 = S2 * invBF, mK = S1 * invBF;
        float vK = e2 - mK * mK;
        float aK = gK[d] / sqrtf(vK + EPSV);
        float c1 = aQ * aK * 0.125f;      // 1/sqrt(64) folded in
        sC0[d] = bQv * aK * 0.125f;
#pragma unroll
        for (int c = 0; c < 4; ++c) sWq2[d * 4 + c] = c1 * wq[c];
    }
    __syncthreads();

    const int blk = blockIdx.x;               // 192
    const int h = blk / 96, rr = blk % 96;
    const int k = tid;
    float s = 0.f;
    if (rr < 80) {
        const int c = rr >> 4, fl = rr & 15;
        const float* Wsrc = (h ? Wkh : Wkz) + (size_t)fl * 64 * 256;
        for (int d = 0; d < 64; ++d) {
            float coef = (c == 0) ? sC0[d] : sWq2[d * 4 + (c - 1)];
            s = fmaf(coef, Wsrc[d * 256 + k], s);
        }
    }
    WKF[(size_t)(h * 96 + rr) * 256 + k] = (__bf16)s;
}

// ---------------------------------------------------------------------------
// fused_attn v11: 512 blocks x 256 threads; wave = 32 rows; B staged via
// global_load_lds (linear LDS dest, pre-swizzled global src, q^(n&31) =
// conflict-free, verified R3); X read once (a2 K-resident). Phase 2 uses the
// counted-vmcnt schedule: prefetch issued BEFORE the barrier, s_waitcnt
// vmcnt(8) (8 newest stay in flight), raw s_barrier, MFMA, pure s_barrier.
__global__ __launch_bounds__(256, 2) void fused_attn(
        const float* __restrict__ feat, const float* __restrict__ hid,
        const float4* __restrict__ cmd, const __bf16* __restrict__ WV,
        const __bf16* __restrict__ WKF, float* __restrict__ out)
{
    __shared__ __bf16 BUF[32768];             // 64 KiB (dbuf 2x32KB / p1 48KB)
    __shared__ __bf16 WGTs[16 * 132];         // [f][row], stride 132 (bank pad)
    const int tid  = threadIdx.x;
    const int wid  = tid >> 6, lane = tid & 63;
    const int l5   = lane & 31, hi = lane >> 5;
    const int fl   = l5 & 15;
    const bool low = (l5 < 16);
    const int wrow = (blockIdx.x << 7) + (wid << 5);   // wave's 32 rows

    // Staging chunk i (per wave): rows n = wid*2 + i*8 + hi, 64 lanes x 16B =
    // 1KiB linear LDS. Source slot pre-swizzled with involution s^(n&31);
    // reads use the same xor: 32 lanes -> 32 distinct slots, conflict-free.
#define STAGE_CHUNK(SRC, DSTBASE, I) do { \
        int n_ = (wid << 1) + ((I) << 3) + hi; \
        gl_lds16((SRC) + n_ * 256 + ((l5 ^ (n_ & 31)) << 3), \
                 &BUF[(DSTBASE) + (((wid << 1) + ((I) << 3)) << 8)]); \
    } while (0)

    float l_i[16];
    f32x16 s_acc[2];
#pragma unroll
    for (int r = 0; r < 16; ++r) { l_i[r] = 0.f; s_acc[0][r] = 0.f; s_acc[1][r] = 0.f; }

    for (int h = 0; h < 2; ++h) {
        const float* X = h ? hid : feat;
        const __bf16* Wkf = WKF + ((size_t)h * 96 << 8);

        // ---- phase 1: issue WKF staging FIRST, then a2 loads (overlap) ----
        __syncthreads();                      // prior readers of BUF done
#pragma unroll
        for (int i = 0; i < 12; ++i)
            STAGE_CHUNK(Wkf, 0, i);

        // A fragments (32x32x16): row wrow+l5, k = u*16 + hi*8 + j
        bf16x8 a2[16];
#pragma unroll
        for (int u = 0; u < 16; ++u) {
            const float* p = X + ((size_t)(wrow + l5) << 8) + u * 16 + hi * 8;
            float4 x0 = *(const float4*)p;
            float4 x1 = *(const float4*)(p + 4);
            a2[u] = (bf16x8){ (__bf16)x0.x, (__bf16)x0.y, (__bf16)x0.z, (__bf16)x0.w,
                              (__bf16)x1.x, (__bf16)x1.y, (__bf16)x1.z, (__bf16)x1.w };
        }
        __syncthreads();                      // drains staging + a2 loads

        f32x16 acc1[3];
#pragma unroll
        for (int nt = 0; nt < 3; ++nt)
#pragma unroll
            for (int r = 0; r < 16; ++r) acc1[nt][r] = 0.f;
        __builtin_amdgcn_s_setprio(1);
#pragma unroll
        for (int ks = 0; ks < 16; ++ks)
#pragma unroll
            for (int nt = 0; nt < 3; ++nt) {
                int n = nt * 32 + l5;
                bf16x8 b = *(const bf16x8*)&BUF[n * 256 + (((ks * 2 + hi) ^ (n & 31)) << 3)];
                acc1[nt] = MFMA32(a2[ks], b, acc1[nt]);
            }
        __builtin_amdgcn_s_setprio(0);

        // epilogue: combine c-terms, exp, store wgt, accumulate l
#pragma unroll
        for (int g = 0; g < 4; ++g) {
            bf16x4 wv4;
#pragma unroll
            for (int j = 0; j < 4; ++j) {
                const int r = g * 4 + j;
                const int row32 = j + 8 * g + 4 * hi;
                float4 cm = cmd[wrow + row32];
                float e0, e1, t0[3], t1[3];
#pragma unroll
                for (int nt = 0; nt < 3; ++nt) {
                    e0 = acc1[nt][r];
                    e1 = __shfl_xor(e0, 16);
                    t0[nt] = low ? e0 : e1;
                    t1[nt] = low ? e1 : e0;
                }
                float sc = t0[0] + cm.x * t1[0] + cm.y * t0[1]
                                 + cm.z * t1[1] + cm.w * t0[2];
                float w = __expf(sc);
                wv4[j] = (__bf16)w;
                float ws = w;
                ws += __shfl_xor(ws, 1); ws += __shfl_xor(ws, 2);
                ws += __shfl_xor(ws, 4); ws += __shfl_xor(ws, 8);
                l_i[r] += ws;
            }
            if (low) *(bf16x4*)&WGTs[fl * 132 + (wid << 5) + 8 * g + 4 * hi] = wv4;
        }

        __syncthreads();                      // phase-1 BUF reads done (full drain, 1x/half)

        // stage first V tile of this half -> buf0
        {
            const __bf16* base = WV + ((size_t)(h * 16) << 14);
#pragma unroll
            for (int i = 0; i < 8; ++i)
                STAGE_CHUNK(base, 0, i);
        }

        // ---- phase 2: 16 V tiles, counted-vmcnt schedule ----
        // iter f2: [issue next tile] ; vmcnt(8|0) ; s_barrier ; MFMA cur ;
        //          epilogue ; s_barrier (pure, closes WAR window).
        for (int f2 = 0; f2 < 16; ++f2) {
            const int bufsel = (f2 & 1) << 14;
            if (f2 < 15) {                    // prefetch next tile into other buf
                const __bf16* base = WV + ((size_t)(h * 16 + f2 + 1) << 14);
                const int nsel = bufsel ^ 16384;
#pragma unroll
                for (int i = 0; i < 8; ++i)
                    STAGE_CHUNK(base, nsel, i);
                asm volatile("s_waitcnt vmcnt(8)");   // cur tile retired; 8 newest fly
            } else {
                asm volatile("s_waitcnt vmcnt(0)");   // last tile (issued 1 phase ago)
            }
            __builtin_amdgcn_sched_barrier(0);
            __builtin_amdgcn_s_barrier();             // cur buf staged by all waves
            __builtin_amdgcn_sched_barrier(0);

            f32x16 acc2[2];
#pragma unroll
            for (int r = 0; r < 16; ++r) { acc2[0][r] = 0.f; acc2[1][r] = 0.f; }
            __builtin_amdgcn_s_setprio(1);
#pragma unroll
            for (int ks = 0; ks < 16; ++ks)
#pragma unroll
                for (int nt = 0; nt < 2; ++nt) {
                    int n = nt * 32 + l5;
                    bf16x8 b = *(const bf16x8*)&BUF[bufsel + n * 256
                                                    + (((ks * 2 + hi) ^ (n & 31)) << 3)];
                    acc2[nt] = MFMA32(a2[ks], b, acc2[nt]);
                }
            __builtin_amdgcn_s_setprio(0);
#pragma unroll
            for (int g = 0; g < 4; ++g) {
                bf16x4 wv = *(const bf16x4*)&WGTs[f2 * 132 + (wid << 5) + 8 * g + 4 * hi];
#pragma unroll
                for (int j = 0; j < 4; ++j) {
                    float w = (float)wv[j];
                    s_acc[0][g * 4 + j] += w * acc2[0][g * 4 + j];
                    s_acc[1][g * 4 + j] += w * acc2[1][g * 4 + j];
                }
            }
            __builtin_amdgcn_sched_barrier(0);
            __builtin_amdgcn_s_barrier();             // all waves done reading cur buf
            __builtin_amdgcn_sched_barrier(0);
        }
    }
#undef STAGE_CHUNK

    // ---- epilogue: divide by l, store ----
#pragma unroll
    for (int g = 0; g < 4; ++g)
#pragma unroll
        for (int j = 0; j < 4; ++j) {
            const int r = g * 4 + j;
            float inv = 1.0f / l_i[r];
            size_t row = (size_t)(wrow + j + 8 * g + 4 * hi);
            out[(row << 6) + l5]      = s_acc[0][r] * inv;
            out[(row << 6) + 32 + l5] = s_acc[1][r] * inv;
        }
}

// ---------------------------------------------------------------------------
extern "C" void kernel_launch(void* const* d_in, const int* in_sizes, int n_in,
                              void* d_out, int out_size, void* d_ws, size_t ws_size,
                              hipStream_t stream)
{
    (void)in_sizes; (void)n_in; (void)out_size; (void)ws_size;
    const float* feature = (const float*)d_in[0];
    const float* hidden  = (const float*)d_in[1];
    const float* command = (const float*)d_in[2];
    const float* Wq      = (const float*)d_in[3];
    const float* Wkz     = (const float*)d_in[4];
    const float* Wkh     = (const float*)d_in[5];
    const float* Wvz     = (const float*)d_in[6];
    const float* Wvh     = (const float*)d_in[7];
    const float* gammaQ  = (const float*)d_in[8];
    const float* betaQ   = (const float*)d_in[9];
    const float* gammaK  = (const float*)d_in[10];
    const float* betaK   = (const float*)d_in[11];

    char* ws = (char*)d_ws;
    __bf16* WV   = (__bf16*)(ws + WS_WV);
    __bf16* WKF  = (__bf16*)(ws + WS_WKF);
    float*  G    = (float*)(ws + WS_G);
    float*  CS   = (float*)(ws + WS_CS);
    float*  CMDP = (float*)(ws + WS_CMDP);
    float*  Tj   = (float*)(ws + WS_T);
    float*  Uj   = (float*)(ws + WS_U);
    float*  outp = (float*)d_out;
    __bf16* Gp   = (__bf16*)d_out;            // 16 MB scratch before final write

    hipMemsetAsync(ws + WS_CS, 0, 0x800, stream);
    setup1<<<416, 512, 0, stream>>>(feature, hidden, (const float4*)command,
                                    Wvz, Wvh, WV, CMDP, CS, Gp);
    gram_reduce<<<512, 256, 0, stream>>>(Gp, G);
    rowstats<<<256, 256, 0, stream>>>(Wkz, Wkh, G, CS, Tj, Uj);
    foldK<<<192, 256, 0, stream>>>(Wkz, Wkh, Wq, gammaQ, betaQ, gammaK, betaK,
                                   CMDP, Tj, Uj, WKF);
    fused_attn<<<512, 256, 0, stream>>>(feature, hidden, (const float4*)command,
                                        WV, WKF, outp);
}